// Round 1
// baseline (638.592 us; speedup 1.0000x reference)
//
#include <hip/hip_runtime.h>
#include <hip/hip_bf16.h>
#include <math.h>

// Problem constants (fixed by setup_inputs)
constexpr int B    = 4;
constexpr int N    = 8192;
constexpr int COUT = 64;
constexpr int E    = B * N * 32;      // 1048576 edges
constexpr int PERB = N * 32;          // 262144 elements per (b,o) norm group
constexpr int TILES  = E / 16;        // 65536 16-edge tiles
constexpr int TPB    = 64;            // tiles per block (all stages)
constexpr int BLOCKS = TILES / TPB;   // 1024 (256 per batch)
constexpr int TPW16  = 16;            // tiles/wave for 4-wave kernels (stage_last)
constexpr int TPW8   = 8;             // tiles/wave for 8-wave kernels (stage1, stage)
constexpr float EPS   = 1e-5f;
constexpr float SLOPE = 0.1f;

// Tiled-pack activation layout (bf16):
//   addr(c, e) = (e>>4)*1024 + (c>>3)*128 + (e&15)*8 + (c&7)    [ushort units]
// -> MFMA B-frag (8 ch of one edge) = one 16B load; C-store = 8B per m-tile.

typedef __attribute__((ext_vector_type(8))) short short8;
typedef __attribute__((ext_vector_type(4))) float f32x4;
#define MFMA16 __builtin_amdgcn_mfma_f32_16x16x32_bf16

union S8 { short8 s; unsigned int u[4]; };

__device__ __forceinline__ float bflo(unsigned int u) {
    union { unsigned int x; float f; } v; v.x = u << 16; return v.f;
}
__device__ __forceinline__ float bfhi(unsigned int u) {
    union { unsigned int x; float f; } v; v.x = u & 0xFFFF0000u; return v.f;
}
// packed f32x2 -> bf16x2 (RTNE); low 16 bits = a
__device__ __forceinline__ unsigned int pk2(float a, float b) {
    union { __hip_bfloat162 h; unsigned int u; } v;
    v.h = __float22bfloat162_rn(make_float2(a, b));
    return v.u;
}
__device__ __forceinline__ float lrelu(float z) {
    return fmaxf(z, SLOPE * z);
}
__device__ __forceinline__ short8 pack8(const float* f) {
    S8 r;
#pragma unroll
    for (int i = 0; i < 4; ++i) r.u[i] = pk2(f[2 * i], f[2 * i + 1]);
    return r.s;
}
// unpack 8 bf16, apply per-channel scale/shift + leaky relu, repack bf16
__device__ __forceinline__ short8 xform(uint4 raw, const float* sc, const float* sh) {
    unsigned int w[4] = {raw.x, raw.y, raw.z, raw.w};
    S8 r;
#pragma unroll
    for (int i = 0; i < 4; ++i) {
        float z0 = fmaf(bflo(w[i]), sc[2 * i],     sh[2 * i]);
        float z1 = fmaf(bfhi(w[i]), sc[2 * i + 1], sh[2 * i + 1]);
        r.u[i] = pk2(lrelu(z0), lrelu(z1));
    }
    return r.s;
}

// ---------------------------------------------------------------------------
__global__ void detect_i32(const unsigned int* __restrict__ w, int* __restrict__ flag) {
    unsigned long long m = __ballot(w[2 * threadIdx.x + 1] != 0u);
    if (threadIdx.x == 0) *flag = (m != 0ull) ? 1 : 0;
}

// ---------------------------------------------------------------------------
// Shared epilogue: per-(b,o) sum/sumsq partials -> partials[ablk][o*2+{0,1}]
// NW = waves per block (4 for 256-thread kernels, 8 for 512-thread kernels).
template<int NW>
__device__ __forceinline__ void stats_epilogue(
        float (&sacc)[4][4], float (&s2acc)[4][4],
        int tid, int wv, int col, int quad, int ablk,
        float* __restrict__ partials) {
    __shared__ float lds[2][NW][64];
#pragma unroll
    for (int m = 0; m < 4; ++m)
#pragma unroll
        for (int r = 0; r < 4; ++r) {
            float s = sacc[m][r], s2 = s2acc[m][r];
#pragma unroll
            for (int d = 1; d < 16; d <<= 1) {
                s  += __shfl_xor(s,  d, 16);
                s2 += __shfl_xor(s2, d, 16);
            }
            if (col == 0) {
                int o = m * 16 + quad * 4 + r;
                lds[0][wv][o] = s;
                lds[1][wv][o] = s2;
            }
        }
    __syncthreads();
    if (tid < 64) {
        float s = 0.f, s2 = 0.f;
#pragma unroll
        for (int w = 0; w < NW; ++w) { s += lds[0][w][tid]; s2 += lds[1][w][tid]; }
        ((float2*)(partials + (size_t)ablk * 128))[tid] = make_float2(s, s2);
    }
}

// ---------------------------------------------------------------------------
// Layer 1: gather + concat + MFMA (K=35 padded to 64). Software-pipelined:
// edge index 2-deep, signal/ef 1-deep prefetch (clamped, always in-bounds).
// 512-thread blocks (8 waves, 8 tiles/wave): 8192 waves total -> 32 waves/CU
// potential (was 4096 waves / 50% cap) to hide the random-gather L2/L3 latency.
// __launch_bounds__(512,8) pins VGPR <= 64 so 8 waves/SIMD actually fit.
__global__ __launch_bounds__(512, 8) void mfma_stage1(
        const float* __restrict__ signal,   // (BN, 32)
        const void*  __restrict__ edges,
        const float* __restrict__ ef,       // (E, 3)
        const float* __restrict__ W1,       // (64, 35)
        unsigned short* __restrict__ Y,
        const int* __restrict__ flag,
        float* __restrict__ partials) {
    const int tid = threadIdx.x, lane = tid & 63, wv = tid >> 6;
    const int col = lane & 15, quad = lane >> 4;

    short8 afrag[4][2];
#pragma unroll
    for (int m = 0; m < 4; ++m) {
        const float* wr = W1 + (m * 16 + col) * 35;
        float f[8];
#pragma unroll
        for (int j = 0; j < 8; ++j) f[j] = wr[quad * 8 + j];
        afrag[m][0] = pack8(f);
#pragma unroll
        for (int j = 0; j < 8; ++j) f[j] = (quad == 0 && j < 3) ? wr[32 + j] : 0.f;
        afrag[m][1] = pack8(f);
    }
    const bool is32 = (*flag != 0);
    const int* ip = (const int*)edges;
    const long long* lp = (const long long*)edges;

    float sacc[4][4] = {{0.f}}, s2acc[4][4] = {{0.f}};
    const int tile0 = blockIdx.x * TPB + wv * TPW8;
    const int eW = tile0 * 16 + col;      // this lane's edge for tile ti: eW + 16*ti

    // pipeline preload (edges/ef are stream-once: non-temporal so they don't
    // evict the hot 4.2 MB signal table from L2)
    long long idxA = is32 ? (long long)__builtin_nontemporal_load(&ip[eW])
                          : __builtin_nontemporal_load(&lp[eW]);
    const int eB0 = min(eW + 16, E - 1);
    long long idxB = is32 ? (long long)__builtin_nontemporal_load(&ip[eB0])
                          : __builtin_nontemporal_load(&lp[eB0]);
    const float* spA = signal + idxA * 32 + quad * 8;
    float4 sA0 = *(const float4*)spA;
    float4 sA1 = *(const float4*)(spA + 4);
    float efA0 = 0.f, efA1 = 0.f, efA2 = 0.f;
    if (quad == 0) {
        const float* p = ef + (size_t)eW * 3;
        efA0 = __builtin_nontemporal_load(p);
        efA1 = __builtin_nontemporal_load(p + 1);
        efA2 = __builtin_nontemporal_load(p + 2);
    }

    for (int ti = 0; ti < TPW8; ++ti) {
        const int eCur = eW + ti * 16;
        // prefetch idx two ahead, signal/ef one ahead
        const int eI = min(eCur + 32, E - 1);
        long long idxC = is32 ? (long long)__builtin_nontemporal_load(&ip[eI])
                              : __builtin_nontemporal_load(&lp[eI]);
        const float* spB = signal + idxB * 32 + quad * 8;
        float4 sB0 = *(const float4*)spB;
        float4 sB1 = *(const float4*)(spB + 4);
        float efB0 = 0.f, efB1 = 0.f, efB2 = 0.f;
        if (quad == 0) {
            const float* p = ef + (size_t)min(eCur + 16, E - 1) * 3;
            efB0 = __builtin_nontemporal_load(p);
            efB1 = __builtin_nontemporal_load(p + 1);
            efB2 = __builtin_nontemporal_load(p + 2);
        }
        // compute current tile from A-buffers
        float f[8] = {sA0.x, sA0.y, sA0.z, sA0.w, sA1.x, sA1.y, sA1.z, sA1.w};
        short8 b0 = pack8(f);
        float g[8] = {efA0, efA1, efA2, 0.f, 0.f, 0.f, 0.f, 0.f};
        short8 b1 = pack8(g);

        unsigned short* tp = Y + (size_t)(tile0 + ti) * 1024;
#pragma unroll
        for (int m = 0; m < 4; ++m) {
            f32x4 acc = {0.f, 0.f, 0.f, 0.f};
            acc = MFMA16(afrag[m][0], b0, acc, 0, 0, 0);
            acc = MFMA16(afrag[m][1], b1, acc, 0, 0, 0);
            *(uint2*)(tp + (m * 2 + (quad >> 1)) * 128 + col * 8 + (quad & 1) * 4) =
                make_uint2(pk2(acc[0], acc[1]), pk2(acc[2], acc[3]));
#pragma unroll
            for (int r = 0; r < 4; ++r) {
                float v = acc[r];
                sacc[m][r] += v;
                s2acc[m][r] = fmaf(v, v, s2acc[m][r]);
            }
        }
        // rotate pipeline
        sA0 = sB0; sA1 = sB1;
        efA0 = efB0; efA1 = efB1; efA2 = efB2;
        idxB = idxC;
    }
    stats_epilogue<8>(sacc, s2acc, tid, wv, col, quad, blockIdx.x, partials);
}

// ---------------------------------------------------------------------------
// Layer 2: in-place TP GEMM: Y[o] = W * lrelu(scale*Y + shift), + stats.
// dir=1 walks blocks in reverse (LLC serpentine). One-tile-deep prefetch.
// 512-thread blocks (8 waves, 8 tiles/wave) for the same occupancy reason.
__global__ __launch_bounds__(512, 8) void mfma_stage(
        unsigned short* __restrict__ Y,         // in-place (per-tile wave-exclusive)
        const float* __restrict__ W,            // (64, 64)
        const float* __restrict__ scale,        // (B, 64)
        const float* __restrict__ shift,
        float* __restrict__ partials,
        const int dir) {
    const int tid = threadIdx.x, lane = tid & 63, wv = tid >> 6;
    const int col = lane & 15, quad = lane >> 4;
    const int ablk = dir ? (BLOCKS - 1 - blockIdx.x) : blockIdx.x;
    const int b    = ablk >> 8;                 // 256 blocks per batch

    short8 afrag[4][2];
#pragma unroll
    for (int m = 0; m < 4; ++m)
#pragma unroll
        for (int kc = 0; kc < 2; ++kc) {
            const float4* wp = (const float4*)(W + (m * 16 + col) * 64 + kc * 32 + quad * 8);
            float4 w0 = wp[0], w1 = wp[1];
            float f[8] = {w0.x, w0.y, w0.z, w0.w, w1.x, w1.y, w1.z, w1.w};
            afrag[m][kc] = pack8(f);
        }
    float sc[2][8], sh[2][8];
#pragma unroll
    for (int kc = 0; kc < 2; ++kc) {
        const int c0 = (kc * 4 + quad) * 8;
#pragma unroll
        for (int j = 0; j < 8; ++j) {
            sc[kc][j] = scale[b * COUT + c0 + j];
            sh[kc][j] = shift[b * COUT + c0 + j];
        }
    }
    float sacc[4][4] = {{0.f}}, s2acc[4][4] = {{0.f}};
    const int tile0 = ablk * TPB + wv * TPW8;
    const int off0 = quad * 128 + col * 8;

    // pipeline preload
    const unsigned short* tpA = Y + (size_t)tile0 * 1024;
    uint4 pA0 = *(const uint4*)(tpA + off0);
    uint4 pA1 = *(const uint4*)(tpA + 512 + off0);

    for (int ti = 0; ti < TPW8; ++ti) {
        // prefetch next tile (clamped: last iter re-reads own last tile, discarded)
        const unsigned short* tpB = Y + (size_t)(tile0 + min(ti + 1, TPW8 - 1)) * 1024;
        uint4 pB0 = *(const uint4*)(tpB + off0);
        uint4 pB1 = *(const uint4*)(tpB + 512 + off0);

        short8 b0 = xform(pA0, sc[0], sh[0]);
        short8 b1 = xform(pA1, sc[1], sh[1]);
        unsigned short* tp = Y + (size_t)(tile0 + ti) * 1024;
#pragma unroll
        for (int m = 0; m < 4; ++m) {
            f32x4 acc = {0.f, 0.f, 0.f, 0.f};
            acc = MFMA16(afrag[m][0], b0, acc, 0, 0, 0);
            acc = MFMA16(afrag[m][1], b1, acc, 0, 0, 0);
            *(uint2*)(tp + (m * 2 + (quad >> 1)) * 128 + col * 8 + (quad & 1) * 4) =
                make_uint2(pk2(acc[0], acc[1]), pk2(acc[2], acc[3]));
#pragma unroll
            for (int r = 0; r < 4; ++r) {
                float v = acc[r];
                sacc[m][r] += v;
                s2acc[m][r] = fmaf(v, v, s2acc[m][r]);
            }
        }
        pA0 = pB0; pA1 = pB1;
    }
    stats_epilogue<8>(sacc, s2acc, tid, wv, col, quad, ablk, partials);
}

// ---------------------------------------------------------------------------
// Layer 3 (last): GEMM without Y writeback. Per bn pair (2 tiles) tracks fp32
// max/min of pre-norm y3; per-lane values go through a WAVE-PRIVATE col-swizzled
// LDS slice (no cross-wave traffic -> no barriers), each lane then owns one
// output channel and writes the compact R record (64 mx + 64 mn floats) into
// the wave's OWN just-consumed tile 2*pr region. Race-free by program order.
// Stays at 256 threads: its 32 KB wave-private LDS would cap occupancy at the
// same 16 waves/CU regardless of block shape, so no gain from 512 threads.
__global__ __launch_bounds__(256) void mfma_stage_last(
        unsigned short* __restrict__ Y,
        const float* __restrict__ W,
        const float* __restrict__ scale,
        const float* __restrict__ shift,
        float* __restrict__ partials) {
    const int tid = threadIdx.x, lane = tid & 63, wv = tid >> 6;
    const int col = lane & 15, quad = lane >> 4;
    const int ablk = blockIdx.x;
    const int b    = ablk >> 8;

    short8 afrag[4][2];
#pragma unroll
    for (int m = 0; m < 4; ++m)
#pragma unroll
        for (int kc = 0; kc < 2; ++kc) {
            const float4* wp = (const float4*)(W + (m * 16 + col) * 64 + kc * 32 + quad * 8);
            float4 w0 = wp[0], w1 = wp[1];
            float f[8] = {w0.x, w0.y, w0.z, w0.w, w1.x, w1.y, w1.z, w1.w};
            afrag[m][kc] = pack8(f);
        }
    float sc[2][8], sh[2][8];
#pragma unroll
    for (int kc = 0; kc < 2; ++kc) {
        const int c0 = (kc * 4 + quad) * 8;
#pragma unroll
        for (int j = 0; j < 8; ++j) {
            sc[kc][j] = scale[b * COUT + c0 + j];
            sh[kc][j] = shift[b * COUT + c0 + j];
        }
    }
    float sacc[4][4] = {{0.f}}, s2acc[4][4] = {{0.f}};
    const int tile0 = ablk * TPB + wv * TPW16;
    const int off0 = quad * 128 + col * 8;

    // wave-private slices: [wv][col(16)][o(64) x (mx,mn)] fp32, col-swizzled
    __shared__ float ldsP[4][2048];              // 32 KB
    float* P = ldsP[wv];
    const int swz = (col & 7) << 2;

    const unsigned short* tpA = Y + (size_t)tile0 * 1024;
    uint4 pA0 = *(const uint4*)(tpA + off0);
    uint4 pA1 = *(const uint4*)(tpA + 512 + off0);

    for (int pr = 0; pr < TPW16 / 2; ++pr) {
        float mx[4][4], mn[4][4];
#pragma unroll
        for (int m = 0; m < 4; ++m)
#pragma unroll
            for (int r = 0; r < 4; ++r) { mx[m][r] = -1e30f; mn[m][r] = 1e30f; }

#pragma unroll
        for (int hf = 0; hf < 2; ++hf) {
            const int ti = pr * 2 + hf;
            const unsigned short* tpB = Y + (size_t)(tile0 + min(ti + 1, TPW16 - 1)) * 1024;
            uint4 pB0 = *(const uint4*)(tpB + off0);
            uint4 pB1 = *(const uint4*)(tpB + 512 + off0);

            short8 b0 = xform(pA0, sc[0], sh[0]);
            short8 b1 = xform(pA1, sc[1], sh[1]);
#pragma unroll
            for (int m = 0; m < 4; ++m) {
                f32x4 acc = {0.f, 0.f, 0.f, 0.f};
                acc = MFMA16(afrag[m][0], b0, acc, 0, 0, 0);
                acc = MFMA16(afrag[m][1], b1, acc, 0, 0, 0);
#pragma unroll
                for (int r = 0; r < 4; ++r) {
                    float v = acc[r];
                    sacc[m][r] += v;
                    s2acc[m][r] = fmaf(v, v, s2acc[m][r]);
                    mx[m][r] = fmaxf(mx[m][r], v);
                    mn[m][r] = fminf(mn[m][r], v);
                }
            }
            pA0 = pB0; pA1 = pB1;
        }
        // stash per-lane (mx,mn) into the wave slice (8x ds_write_b128, 2-way max)
#pragma unroll
        for (int m = 0; m < 4; ++m) {
            const int fi0 = col * 128 + m * 32 + quad * 8;
            float4 lo = {mx[m][0], mn[m][0], mx[m][1], mn[m][1]};
            float4 hi = {mx[m][2], mn[m][2], mx[m][3], mn[m][3]};
            *(float4*)&P[fi0 ^ swz] = lo;
            *(float4*)&P[(fi0 + 4) ^ swz] = hi;
        }
        __builtin_amdgcn_wave_barrier();
        // wave-local reduce over the 16 edge-columns: lane owns channel o=lane
        float gx = -1e30f, gn = 1e30f;
#pragma unroll
        for (int cc = 0; cc < 16; ++cc) {
            const float2 v = *(const float2*)&P[(cc * 128 + lane * 2) ^ ((cc & 7) << 2)];
            gx = fmaxf(gx, v.x);
            gn = fminf(gn, v.y);
        }
        __builtin_amdgcn_wave_barrier();
        // compact R record into this wave's OWN already-read tile 2*pr region
        float* R = (float*)(Y + (size_t)(tile0 + 2 * pr) * 1024);
        R[lane]      = gx;
        R[64 + lane] = gn;
    }
    stats_epilogue<4>(sacc, s2acc, tid, wv, col, quad, ablk, partials);
}

// ---------------------------------------------------------------------------
// Parallel finalize: one block per (o,b); 256 threads sum that batch's partials.
__global__ __launch_bounds__(256) void finalize_k(
        const float* __restrict__ partials,
        const float* __restrict__ gamma,
        const float* __restrict__ beta,
        float* __restrict__ scale,
        float* __restrict__ shift) {
    const int g = blockIdx.x;        // 0..255
    const int o = g >> 2, b = g & 3;
    const int k = threadIdx.x;       // 0..255
    const float* p = partials + (size_t)(b * 256 + k) * 128 + o * 2;
    float s = p[0], s2 = p[1];
    __shared__ float red[512];
    red[k] = s; red[256 + k] = s2;
    __syncthreads();
    for (int st = 128; st > 0; st >>= 1) {
        if (k < st) { red[k] += red[k + st]; red[256 + k] += red[256 + k + st]; }
        __syncthreads();
    }
    if (k == 0) {
        const float inv_n = 1.f / (float)PERB;
        float mean = red[0] * inv_n;
        float var  = red[256] * inv_n - mean * mean;
        float inv  = rsqrtf(var + EPS);
        float scv  = gamma[o] * inv;
        scale[b * COUT + o] = scv;
        shift[b * COUT + o] = beta[o] - mean * scv;
    }
}

// ---------------------------------------------------------------------------
// Final pool: read compact R records (fp32 max/min of pre-norm y3) from the
// per-(wv,pr) slots inside Y, apply affine norm (sign-aware), one lrelu.
__global__ __launch_bounds__(256) void pool_final(
        const unsigned short* __restrict__ Y,
        const float* __restrict__ scale,
        const float* __restrict__ shift,
        float* __restrict__ out) {
    const int t  = blockIdx.x * 256 + threadIdx.x;   // 0..262143
    const int og = t & 7;
    const int bn = t >> 3;
    const int b  = bn >> 13;
    const int ablk = bn >> 5;
    const int wv   = (bn >> 3) & 3;
    const int pr   = bn & 7;
    const float* base =
        (const float*)(Y + (size_t)(ablk * TPB + wv * TPW16 + 2 * pr) * 1024);
    float4 x0 = *(const float4*)(base + og * 8);
    float4 x1 = *(const float4*)(base + og * 8 + 4);
    float4 n0 = *(const float4*)(base + 64 + og * 8);
    float4 n1 = *(const float4*)(base + 68 + og * 8);
    float mxv[8] = {x0.x, x0.y, x0.z, x0.w, x1.x, x1.y, x1.z, x1.w};
    float mnv[8] = {n0.x, n0.y, n0.z, n0.w, n1.x, n1.y, n1.z, n1.w};
    float r[8];
#pragma unroll
    for (int j = 0; j < 8; ++j) {
        const int o = og * 8 + j;
        const float s = scale[b * COUT + o], h = shift[b * COUT + o];
        float m = (s >= 0.f ? mxv[j] : mnv[j]) * s + h;
        r[j] = lrelu(m);
    }
    float4* q = (float4*)(out + (size_t)bn * COUT + og * 8);
    q[0] = make_float4(r[0], r[1], r[2], r[3]);
    q[1] = make_float4(r[4], r[5], r[6], r[7]);
}

// ---------------------------------------------------------------------------
extern "C" void kernel_launch(void* const* d_in, const int* in_sizes, int n_in,
                              void* d_out, int out_size, void* d_ws, size_t ws_size,
                              hipStream_t stream) {
    const float* signal = (const float*)d_in[0];
    const void*  edges  = d_in[1];
    const float* ef     = (const float*)d_in[2];
    const float* W1 = (const float*)d_in[4];
    const float* g1 = (const float*)d_in[5];
    const float* b1 = (const float*)d_in[6];
    const float* W2 = (const float*)d_in[7];
    const float* g2 = (const float*)d_in[8];
    const float* b2 = (const float*)d_in[9];
    const float* W3 = (const float*)d_in[10];
    const float* g3 = (const float*)d_in[11];
    const float* b3 = (const float*)d_in[12];
    float* out = (float*)d_out;

    // Workspace: Y (134.2 MB) + partials (512 KB) + flag + 6x256 scale/shift
    unsigned short* Y = (unsigned short*)d_ws;
    const size_t YB = (size_t)E * COUT * sizeof(unsigned short);
    float* partials = (float*)((char*)d_ws + YB);
    char*  tail = (char*)d_ws + YB + (size_t)BLOCKS * 128 * sizeof(float);
    int*   flag = (int*)tail;
    float* ss   = (float*)(tail + 256);
    float *sc0 = ss,        *sh0 = ss + 256;
    float *sc1 = ss + 512,  *sh1 = ss + 768;
    float *sc2 = ss + 1024, *sh2 = ss + 1280;

    detect_i32<<<1, 64, 0, stream>>>((const unsigned int*)edges, flag);

    mfma_stage1<<<BLOCKS, 512, 0, stream>>>(signal, edges, ef, W1, Y, flag, partials);
    finalize_k<<<256, 256, 0, stream>>>(partials, g1, b1, sc0, sh0);

    mfma_stage<<<BLOCKS, 512, 0, stream>>>(Y, W2, sc0, sh0, partials, 1);
    finalize_k<<<256, 256, 0, stream>>>(partials, g2, b2, sc1, sh1);

    mfma_stage_last<<<BLOCKS, 256, 0, stream>>>(Y, W3, sc1, sh1, partials);
    finalize_k<<<256, 256, 0, stream>>>(partials, g3, b3, sc2, sh2);

    pool_final<<<1024, 256, 0, stream>>>(Y, sc2, sh2, out);
}

// Round 2
// 306.049 us; speedup vs baseline: 2.0866x; 2.0866x over previous
//
#include <hip/hip_runtime.h>
#include <hip/hip_bf16.h>
#include <math.h>

// Problem constants (fixed by setup_inputs)
constexpr int B    = 4;
constexpr int N    = 8192;
constexpr int COUT = 64;
constexpr int E    = B * N * 32;      // 1048576 edges
constexpr int PERB = N * 32;          // 262144 elements per (b,o) norm group
constexpr int TILES  = E / 16;        // 65536 16-edge tiles
constexpr int TPW    = 16;            // tiles per wave (8 bn pairs)
constexpr int TPB    = TPW * 4;       // 64 tiles per block
constexpr int BLOCKS = TILES / TPB;   // 1024 (256 per batch)
constexpr float EPS   = 1e-5f;
constexpr float SLOPE = 0.1f;

// Tiled-pack activation layout (bf16):
//   addr(c, e) = (e>>4)*1024 + (c>>3)*128 + (e&15)*8 + (c&7)    [ushort units]
// -> MFMA B-frag (8 ch of one edge) = one 16B load; C-store = 8B per m-tile.

typedef __attribute__((ext_vector_type(8))) short short8;
typedef __attribute__((ext_vector_type(4))) float f32x4;
#define MFMA16 __builtin_amdgcn_mfma_f32_16x16x32_bf16

union S8 { short8 s; unsigned int u[4]; };

__device__ __forceinline__ float bflo(unsigned int u) {
    union { unsigned int x; float f; } v; v.x = u << 16; return v.f;
}
__device__ __forceinline__ float bfhi(unsigned int u) {
    union { unsigned int x; float f; } v; v.x = u & 0xFFFF0000u; return v.f;
}
// packed f32x2 -> bf16x2 (RTNE); low 16 bits = a
__device__ __forceinline__ unsigned int pk2(float a, float b) {
    union { __hip_bfloat162 h; unsigned int u; } v;
    v.h = __float22bfloat162_rn(make_float2(a, b));
    return v.u;
}
__device__ __forceinline__ float lrelu(float z) {
    return fmaxf(z, SLOPE * z);
}
__device__ __forceinline__ short8 pack8(const float* f) {
    S8 r;
#pragma unroll
    for (int i = 0; i < 4; ++i) r.u[i] = pk2(f[2 * i], f[2 * i + 1]);
    return r.s;
}
// unpack 8 bf16, apply per-channel scale/shift + leaky relu, repack bf16
__device__ __forceinline__ short8 xform(uint4 raw, const float* sc, const float* sh) {
    unsigned int w[4] = {raw.x, raw.y, raw.z, raw.w};
    S8 r;
#pragma unroll
    for (int i = 0; i < 4; ++i) {
        float z0 = fmaf(bflo(w[i]), sc[2 * i],     sh[2 * i]);
        float z1 = fmaf(bfhi(w[i]), sc[2 * i + 1], sh[2 * i + 1]);
        r.u[i] = pk2(lrelu(z0), lrelu(z1));
    }
    return r.s;
}

// ---------------------------------------------------------------------------
__global__ void detect_i32(const unsigned int* __restrict__ w, int* __restrict__ flag) {
    unsigned long long m = __ballot(w[2 * threadIdx.x + 1] != 0u);
    if (threadIdx.x == 0) *flag = (m != 0ull) ? 1 : 0;
}

// ---------------------------------------------------------------------------
// Shared epilogue: per-(b,o) sum/sumsq partials -> partials[ablk][o*2+{0,1}]
__device__ __forceinline__ void stats_epilogue(
        float (&sacc)[4][4], float (&s2acc)[4][4],
        int tid, int wv, int col, int quad, int ablk,
        float* __restrict__ partials) {
    __shared__ float lds[2][4][64];
#pragma unroll
    for (int m = 0; m < 4; ++m)
#pragma unroll
        for (int r = 0; r < 4; ++r) {
            float s = sacc[m][r], s2 = s2acc[m][r];
#pragma unroll
            for (int d = 1; d < 16; d <<= 1) {
                s  += __shfl_xor(s,  d, 16);
                s2 += __shfl_xor(s2, d, 16);
            }
            if (col == 0) {
                int o = m * 16 + quad * 4 + r;
                lds[0][wv][o] = s;
                lds[1][wv][o] = s2;
            }
        }
    __syncthreads();
    if (tid < 64) {
        float s  = lds[0][0][tid] + lds[0][1][tid] + lds[0][2][tid] + lds[0][3][tid];
        float s2 = lds[1][0][tid] + lds[1][1][tid] + lds[1][2][tid] + lds[1][3][tid];
        ((float2*)(partials + (size_t)ablk * 128))[tid] = make_float2(s, s2);
    }
}

// ---------------------------------------------------------------------------
// Layer 1: gather + concat + MFMA (K=35 padded to 64). DEPTH=3 software
// pipeline: 3 tiles of gathered signal in registers per wave (48 gathers in
// flight per CU at 16 waves/CU) to hide the L2/L3 random-gather latency.
// Grid supplies only 16 waves/CU (1024 blocks x 4 waves), which tolerates
// VGPR <= 128 -- the ~40 extra pipeline registers are free occupancy-wise.
// __launch_bounds__(256,4) caps the allocator at that budget (NOT (512,8):
// that forced VGPR=32 and spilled everything to scratch, 5x regression).
__global__ __launch_bounds__(256, 4) void mfma_stage1(
        const float* __restrict__ signal,   // (BN, 32)
        const void*  __restrict__ edges,
        const float* __restrict__ ef,       // (E, 3)
        const float* __restrict__ W1,       // (64, 35)
        unsigned short* __restrict__ Y,
        const int* __restrict__ flag,
        float* __restrict__ partials) {
    const int tid = threadIdx.x, lane = tid & 63, wv = tid >> 6;
    const int col = lane & 15, quad = lane >> 4;

    short8 afrag[4][2];
#pragma unroll
    for (int m = 0; m < 4; ++m) {
        const float* wr = W1 + (m * 16 + col) * 35;
        float f[8];
#pragma unroll
        for (int j = 0; j < 8; ++j) f[j] = wr[quad * 8 + j];
        afrag[m][0] = pack8(f);
#pragma unroll
        for (int j = 0; j < 8; ++j) f[j] = (quad == 0 && j < 3) ? wr[32 + j] : 0.f;
        afrag[m][1] = pack8(f);
    }
    const bool is32 = (*flag != 0);
    const int* ip = (const int*)edges;
    const long long* lp = (const long long*)edges;

    float sacc[4][4] = {{0.f}}, s2acc[4][4] = {{0.f}};
    const int tile0 = blockIdx.x * TPB + wv * TPW;
    const int eW = tile0 * 16 + col;      // this lane's edge for tile ti: eW + 16*ti

    constexpr int DEPTH = 3;
    float4 s0[DEPTH], s1[DEPTH];
    float e0[DEPTH], e1[DEPTH], e2[DEPTH];

    // ---- prologue: indices for tiles 0..DEPTH-1 (all in flight), then their
    // signal/ef gathers (edges/ef are stream-once -> nontemporal, keep the hot
    // 4.2 MB signal table in L2). All addresses in-range by construction.
    long long idp[DEPTH];
#pragma unroll
    for (int d = 0; d < DEPTH; ++d) {
        const int e = eW + 16 * d;
        idp[d] = is32 ? (long long)__builtin_nontemporal_load(&ip[e])
                      : __builtin_nontemporal_load(&lp[e]);
    }
#pragma unroll
    for (int d = 0; d < DEPTH; ++d) {
        const float* sp = signal + idp[d] * 32 + quad * 8;
        s0[d] = *(const float4*)sp;
        s1[d] = *(const float4*)(sp + 4);
        e0[d] = e1[d] = e2[d] = 0.f;
        if (quad == 0) {
            const float* p = ef + (size_t)(eW + 16 * d) * 3;
            e0[d] = __builtin_nontemporal_load(p);
            e1[d] = __builtin_nontemporal_load(p + 1);
            e2[d] = __builtin_nontemporal_load(p + 2);
        }
    }
    // index for the next refill (tile DEPTH)
    long long idxN = is32 ? (long long)__builtin_nontemporal_load(&ip[eW + 16 * DEPTH])
                          : __builtin_nontemporal_load(&lp[eW + 16 * DEPTH]);

#pragma unroll
    for (int ti = 0; ti < TPW; ++ti) {
        const int slot = ti % DEPTH;          // static under full unroll
        // grab current tile's values (register renames)
        float4 a0 = s0[slot], a1 = s1[slot];
        float f0 = e0[slot], f1 = e1[slot], f2 = e2[slot];

        // refill slot with tile ti+DEPTH; fetch index for ti+DEPTH+1
        const int tn = ti + DEPTH;
        if (tn < TPW) {
            const float* sp = signal + idxN * 32 + quad * 8;
            s0[slot] = *(const float4*)sp;
            s1[slot] = *(const float4*)(sp + 4);
            if (quad == 0) {
                const float* p = ef + (size_t)(eW + 16 * tn) * 3;
                e0[slot] = __builtin_nontemporal_load(p);
                e1[slot] = __builtin_nontemporal_load(p + 1);
                e2[slot] = __builtin_nontemporal_load(p + 2);
            }
            const int en = min(eW + 16 * (tn + 1), E - 1);
            idxN = is32 ? (long long)__builtin_nontemporal_load(&ip[en])
                        : __builtin_nontemporal_load(&lp[en]);
        }

        // compute current tile
        float f[8] = {a0.x, a0.y, a0.z, a0.w, a1.x, a1.y, a1.z, a1.w};
        short8 b0 = pack8(f);
        float g[8] = {f0, f1, f2, 0.f, 0.f, 0.f, 0.f, 0.f};
        short8 b1 = pack8(g);

        unsigned short* tp = Y + (size_t)(tile0 + ti) * 1024;
#pragma unroll
        for (int m = 0; m < 4; ++m) {
            f32x4 acc = {0.f, 0.f, 0.f, 0.f};
            acc = MFMA16(afrag[m][0], b0, acc, 0, 0, 0);
            acc = MFMA16(afrag[m][1], b1, acc, 0, 0, 0);
            *(uint2*)(tp + (m * 2 + (quad >> 1)) * 128 + col * 8 + (quad & 1) * 4) =
                make_uint2(pk2(acc[0], acc[1]), pk2(acc[2], acc[3]));
#pragma unroll
            for (int r = 0; r < 4; ++r) {
                float v = acc[r];
                sacc[m][r] += v;
                s2acc[m][r] = fmaf(v, v, s2acc[m][r]);
            }
        }
    }
    stats_epilogue(sacc, s2acc, tid, wv, col, quad, blockIdx.x, partials);
}

// ---------------------------------------------------------------------------
// Layer 2: in-place TP GEMM: Y[o] = W * lrelu(scale*Y + shift), + stats.
// dir=1 walks blocks in reverse (LLC serpentine). One-tile-deep prefetch.
__global__ __launch_bounds__(256) void mfma_stage(
        unsigned short* __restrict__ Y,         // in-place (per-tile wave-exclusive)
        const float* __restrict__ W,            // (64, 64)
        const float* __restrict__ scale,        // (B, 64)
        const float* __restrict__ shift,
        float* __restrict__ partials,
        const int dir) {
    const int tid = threadIdx.x, lane = tid & 63, wv = tid >> 6;
    const int col = lane & 15, quad = lane >> 4;
    const int ablk = dir ? (BLOCKS - 1 - blockIdx.x) : blockIdx.x;
    const int b    = ablk >> 8;                 // 256 blocks per batch

    short8 afrag[4][2];
#pragma unroll
    for (int m = 0; m < 4; ++m)
#pragma unroll
        for (int kc = 0; kc < 2; ++kc) {
            const float4* wp = (const float4*)(W + (m * 16 + col) * 64 + kc * 32 + quad * 8);
            float4 w0 = wp[0], w1 = wp[1];
            float f[8] = {w0.x, w0.y, w0.z, w0.w, w1.x, w1.y, w1.z, w1.w};
            afrag[m][kc] = pack8(f);
        }
    float sc[2][8], sh[2][8];
#pragma unroll
    for (int kc = 0; kc < 2; ++kc) {
        const int c0 = (kc * 4 + quad) * 8;
#pragma unroll
        for (int j = 0; j < 8; ++j) {
            sc[kc][j] = scale[b * COUT + c0 + j];
            sh[kc][j] = shift[b * COUT + c0 + j];
        }
    }
    float sacc[4][4] = {{0.f}}, s2acc[4][4] = {{0.f}};
    const int tile0 = ablk * TPB + wv * TPW;
    const int off0 = quad * 128 + col * 8;

    // pipeline preload
    const unsigned short* tpA = Y + (size_t)tile0 * 1024;
    uint4 pA0 = *(const uint4*)(tpA + off0);
    uint4 pA1 = *(const uint4*)(tpA + 512 + off0);

    for (int ti = 0; ti < TPW; ++ti) {
        // prefetch next tile (clamped: last iter re-reads own last tile, discarded)
        const unsigned short* tpB = Y + (size_t)(tile0 + min(ti + 1, TPW - 1)) * 1024;
        uint4 pB0 = *(const uint4*)(tpB + off0);
        uint4 pB1 = *(const uint4*)(tpB + 512 + off0);

        short8 b0 = xform(pA0, sc[0], sh[0]);
        short8 b1 = xform(pA1, sc[1], sh[1]);
        unsigned short* tp = Y + (size_t)(tile0 + ti) * 1024;
#pragma unroll
        for (int m = 0; m < 4; ++m) {
            f32x4 acc = {0.f, 0.f, 0.f, 0.f};
            acc = MFMA16(afrag[m][0], b0, acc, 0, 0, 0);
            acc = MFMA16(afrag[m][1], b1, acc, 0, 0, 0);
            *(uint2*)(tp + (m * 2 + (quad >> 1)) * 128 + col * 8 + (quad & 1) * 4) =
                make_uint2(pk2(acc[0], acc[1]), pk2(acc[2], acc[3]));
#pragma unroll
            for (int r = 0; r < 4; ++r) {
                float v = acc[r];
                sacc[m][r] += v;
                s2acc[m][r] = fmaf(v, v, s2acc[m][r]);
            }
        }
        pA0 = pB0; pA1 = pB1;
    }
    stats_epilogue(sacc, s2acc, tid, wv, col, quad, ablk, partials);
}

// ---------------------------------------------------------------------------
// Layer 3 (last): GEMM without Y writeback. Per bn pair (2 tiles) tracks fp32
// max/min of pre-norm y3; per-lane values go through a WAVE-PRIVATE col-swizzled
// LDS slice (no cross-wave traffic -> no barriers), each lane then owns one
// output channel and writes the compact R record (64 mx + 64 mn floats) into
// the wave's OWN just-consumed tile 2*pr region. Race-free by program order.
__global__ __launch_bounds__(256) void mfma_stage_last(
        unsigned short* __restrict__ Y,
        const float* __restrict__ W,
        const float* __restrict__ scale,
        const float* __restrict__ shift,
        float* __restrict__ partials) {
    const int tid = threadIdx.x, lane = tid & 63, wv = tid >> 6;
    const int col = lane & 15, quad = lane >> 4;
    const int ablk = blockIdx.x;
    const int b    = ablk >> 8;

    short8 afrag[4][2];
#pragma unroll
    for (int m = 0; m < 4; ++m)
#pragma unroll
        for (int kc = 0; kc < 2; ++kc) {
            const float4* wp = (const float4*)(W + (m * 16 + col) * 64 + kc * 32 + quad * 8);
            float4 w0 = wp[0], w1 = wp[1];
            float f[8] = {w0.x, w0.y, w0.z, w0.w, w1.x, w1.y, w1.z, w1.w};
            afrag[m][kc] = pack8(f);
        }
    float sc[2][8], sh[2][8];
#pragma unroll
    for (int kc = 0; kc < 2; ++kc) {
        const int c0 = (kc * 4 + quad) * 8;
#pragma unroll
        for (int j = 0; j < 8; ++j) {
            sc[kc][j] = scale[b * COUT + c0 + j];
            sh[kc][j] = shift[b * COUT + c0 + j];
        }
    }
    float sacc[4][4] = {{0.f}}, s2acc[4][4] = {{0.f}};
    const int tile0 = ablk * TPB + wv * TPW;
    const int off0 = quad * 128 + col * 8;

    // wave-private slices: [wv][col(16)][o(64) x (mx,mn)] fp32, col-swizzled
    __shared__ float ldsP[4][2048];              // 32 KB
    float* P = ldsP[wv];
    const int swz = (col & 7) << 2;

    const unsigned short* tpA = Y + (size_t)tile0 * 1024;
    uint4 pA0 = *(const uint4*)(tpA + off0);
    uint4 pA1 = *(const uint4*)(tpA + 512 + off0);

    for (int pr = 0; pr < TPW / 2; ++pr) {
        float mx[4][4], mn[4][4];
#pragma unroll
        for (int m = 0; m < 4; ++m)
#pragma unroll
            for (int r = 0; r < 4; ++r) { mx[m][r] = -1e30f; mn[m][r] = 1e30f; }

#pragma unroll
        for (int hf = 0; hf < 2; ++hf) {
            const int ti = pr * 2 + hf;
            const unsigned short* tpB = Y + (size_t)(tile0 + min(ti + 1, TPW - 1)) * 1024;
            uint4 pB0 = *(const uint4*)(tpB + off0);
            uint4 pB1 = *(const uint4*)(tpB + 512 + off0);

            short8 b0 = xform(pA0, sc[0], sh[0]);
            short8 b1 = xform(pA1, sc[1], sh[1]);
#pragma unroll
            for (int m = 0; m < 4; ++m) {
                f32x4 acc = {0.f, 0.f, 0.f, 0.f};
                acc = MFMA16(afrag[m][0], b0, acc, 0, 0, 0);
                acc = MFMA16(afrag[m][1], b1, acc, 0, 0, 0);
#pragma unroll
                for (int r = 0; r < 4; ++r) {
                    float v = acc[r];
                    sacc[m][r] += v;
                    s2acc[m][r] = fmaf(v, v, s2acc[m][r]);
                    mx[m][r] = fmaxf(mx[m][r], v);
                    mn[m][r] = fminf(mn[m][r], v);
                }
            }
            pA0 = pB0; pA1 = pB1;
        }
        // stash per-lane (mx,mn) into the wave slice (8x ds_write_b128, 2-way max)
#pragma unroll
        for (int m = 0; m < 4; ++m) {
            const int fi0 = col * 128 + m * 32 + quad * 8;
            float4 lo = {mx[m][0], mn[m][0], mx[m][1], mn[m][1]};
            float4 hi = {mx[m][2], mn[m][2], mx[m][3], mn[m][3]};
            *(float4*)&P[fi0 ^ swz] = lo;
            *(float4*)&P[(fi0 + 4) ^ swz] = hi;
        }
        __builtin_amdgcn_wave_barrier();
        // wave-local reduce over the 16 edge-columns: lane owns channel o=lane
        float gx = -1e30f, gn = 1e30f;
#pragma unroll
        for (int cc = 0; cc < 16; ++cc) {
            const float2 v = *(const float2*)&P[(cc * 128 + lane * 2) ^ ((cc & 7) << 2)];
            gx = fmaxf(gx, v.x);
            gn = fminf(gn, v.y);
        }
        __builtin_amdgcn_wave_barrier();
        // compact R record into this wave's OWN already-read tile 2*pr region
        float* R = (float*)(Y + (size_t)(tile0 + 2 * pr) * 1024);
        R[lane]      = gx;
        R[64 + lane] = gn;
    }
    stats_epilogue(sacc, s2acc, tid, wv, col, quad, ablk, partials);
}

// ---------------------------------------------------------------------------
// Parallel finalize: one block per (o,b); 256 threads sum that batch's partials.
__global__ __launch_bounds__(256) void finalize_k(
        const float* __restrict__ partials,
        const float* __restrict__ gamma,
        const float* __restrict__ beta,
        float* __restrict__ scale,
        float* __restrict__ shift) {
    const int g = blockIdx.x;        // 0..255
    const int o = g >> 2, b = g & 3;
    const int k = threadIdx.x;       // 0..255
    const float* p = partials + (size_t)(b * 256 + k) * 128 + o * 2;
    float s = p[0], s2 = p[1];
    __shared__ float red[512];
    red[k] = s; red[256 + k] = s2;
    __syncthreads();
    for (int st = 128; st > 0; st >>= 1) {
        if (k < st) { red[k] += red[k + st]; red[256 + k] += red[256 + k + st]; }
        __syncthreads();
    }
    if (k == 0) {
        const float inv_n = 1.f / (float)PERB;
        float mean = red[0] * inv_n;
        float var  = red[256] * inv_n - mean * mean;
        float inv  = rsqrtf(var + EPS);
        float scv  = gamma[o] * inv;
        scale[b * COUT + o] = scv;
        shift[b * COUT + o] = beta[o] - mean * scv;
    }
}

// ---------------------------------------------------------------------------
// Final pool: read compact R records (fp32 max/min of pre-norm y3) from the
// per-(wv,pr) slots inside Y, apply affine norm (sign-aware), one lrelu.
__global__ __launch_bounds__(256) void pool_final(
        const unsigned short* __restrict__ Y,
        const float* __restrict__ scale,
        const float* __restrict__ shift,
        float* __restrict__ out) {
    const int t  = blockIdx.x * 256 + threadIdx.x;   // 0..262143
    const int og = t & 7;
    const int bn = t >> 3;
    const int b  = bn >> 13;
    const int ablk = bn >> 5;
    const int wv   = (bn >> 3) & 3;
    const int pr   = bn & 7;
    const float* base =
        (const float*)(Y + (size_t)(ablk * TPB + wv * TPW + 2 * pr) * 1024);
    float4 x0 = *(const float4*)(base + og * 8);
    float4 x1 = *(const float4*)(base + og * 8 + 4);
    float4 n0 = *(const float4*)(base + 64 + og * 8);
    float4 n1 = *(const float4*)(base + 68 + og * 8);
    float mxv[8] = {x0.x, x0.y, x0.z, x0.w, x1.x, x1.y, x1.z, x1.w};
    float mnv[8] = {n0.x, n0.y, n0.z, n0.w, n1.x, n1.y, n1.z, n1.w};
    float r[8];
#pragma unroll
    for (int j = 0; j < 8; ++j) {
        const int o = og * 8 + j;
        const float s = scale[b * COUT + o], h = shift[b * COUT + o];
        float m = (s >= 0.f ? mxv[j] : mnv[j]) * s + h;
        r[j] = lrelu(m);
    }
    float4* q = (float4*)(out + (size_t)bn * COUT + og * 8);
    q[0] = make_float4(r[0], r[1], r[2], r[3]);
    q[1] = make_float4(r[4], r[5], r[6], r[7]);
}

// ---------------------------------------------------------------------------
extern "C" void kernel_launch(void* const* d_in, const int* in_sizes, int n_in,
                              void* d_out, int out_size, void* d_ws, size_t ws_size,
                              hipStream_t stream) {
    const float* signal = (const float*)d_in[0];
    const void*  edges  = d_in[1];
    const float* ef     = (const float*)d_in[2];
    const float* W1 = (const float*)d_in[4];
    const float* g1 = (const float*)d_in[5];
    const float* b1 = (const float*)d_in[6];
    const float* W2 = (const float*)d_in[7];
    const float* g2 = (const float*)d_in[8];
    const float* b2 = (const float*)d_in[9];
    const float* W3 = (const float*)d_in[10];
    const float* g3 = (const float*)d_in[11];
    const float* b3 = (const float*)d_in[12];
    float* out = (float*)d_out;

    // Workspace: Y (134.2 MB) + partials (512 KB) + flag + 6x256 scale/shift
    unsigned short* Y = (unsigned short*)d_ws;
    const size_t YB = (size_t)E * COUT * sizeof(unsigned short);
    float* partials = (float*)((char*)d_ws + YB);
    char*  tail = (char*)d_ws + YB + (size_t)BLOCKS * 128 * sizeof(float);
    int*   flag = (int*)tail;
    float* ss   = (float*)(tail + 256);
    float *sc0 = ss,        *sh0 = ss + 256;
    float *sc1 = ss + 512,  *sh1 = ss + 768;
    float *sc2 = ss + 1024, *sh2 = ss + 1280;

    detect_i32<<<1, 64, 0, stream>>>((const unsigned int*)edges, flag);

    mfma_stage1<<<BLOCKS, 256, 0, stream>>>(signal, edges, ef, W1, Y, flag, partials);
    finalize_k<<<256, 256, 0, stream>>>(partials, g1, b1, sc0, sh0);

    mfma_stage<<<BLOCKS, 256, 0, stream>>>(Y, W2, sc0, sh0, partials, 1);
    finalize_k<<<256, 256, 0, stream>>>(partials, g2, b2, sc1, sh1);

    mfma_stage_last<<<BLOCKS, 256, 0, stream>>>(Y, W3, sc1, sh1, partials);
    finalize_k<<<256, 256, 0, stream>>>(partials, g3, b3, sc2, sh2);

    pool_final<<<1024, 256, 0, stream>>>(Y, sc2, sh2, out);
}

// Round 3
// 194.255 us; speedup vs baseline: 3.2874x; 1.5755x over previous
//
#include <hip/hip_runtime.h>
#include <hip/hip_bf16.h>
#include <math.h>

// Problem constants (fixed by setup_inputs)
constexpr int B    = 4;
constexpr int N    = 8192;
constexpr int COUT = 64;
constexpr int E    = B * N * 32;      // 1048576 edges
constexpr int PERB = N * 32;          // 262144 elements per (b,o) norm group
constexpr int TILES  = E / 16;        // 65536 16-edge tiles
constexpr int TPB    = 64;            // tiles per block (all stages)
constexpr int BLOCKS = TILES / TPB;   // 1024 (256 per batch)
constexpr int TPW16  = 16;            // tiles/wave for 4-wave kernels (stage_last)
constexpr int TPW8   = 8;             // tiles/wave for 8-wave kernels (stage1, stage)
constexpr float EPS   = 1e-5f;
constexpr float SLOPE = 0.1f;

// Tiled-pack activation layout (bf16):
//   addr(c, e) = (e>>4)*1024 + (c>>3)*128 + (e&15)*8 + (c&7)    [ushort units]
// -> MFMA B-frag (8 ch of one edge) = one 16B load; C-store = 8B per m-tile.

typedef __attribute__((ext_vector_type(8))) short short8;
typedef __attribute__((ext_vector_type(4))) float f32x4;
#define MFMA16 __builtin_amdgcn_mfma_f32_16x16x32_bf16

union S8 { short8 s; unsigned int u[4]; };

__device__ __forceinline__ float bflo(unsigned int u) {
    union { unsigned int x; float f; } v; v.x = u << 16; return v.f;
}
__device__ __forceinline__ float bfhi(unsigned int u) {
    union { unsigned int x; float f; } v; v.x = u & 0xFFFF0000u; return v.f;
}
// packed f32x2 -> bf16x2 (RTNE); low 16 bits = a
__device__ __forceinline__ unsigned int pk2(float a, float b) {
    union { __hip_bfloat162 h; unsigned int u; } v;
    v.h = __float22bfloat162_rn(make_float2(a, b));
    return v.u;
}
__device__ __forceinline__ float lrelu(float z) {
    return fmaxf(z, SLOPE * z);
}
__device__ __forceinline__ short8 pack8(const float* f) {
    S8 r;
#pragma unroll
    for (int i = 0; i < 4; ++i) r.u[i] = pk2(f[2 * i], f[2 * i + 1]);
    return r.s;
}
// unpack 8 bf16, apply per-channel scale/shift + leaky relu, repack bf16
__device__ __forceinline__ short8 xform(uint4 raw, const float* sc, const float* sh) {
    unsigned int w[4] = {raw.x, raw.y, raw.z, raw.w};
    S8 r;
#pragma unroll
    for (int i = 0; i < 4; ++i) {
        float z0 = fmaf(bflo(w[i]), sc[2 * i],     sh[2 * i]);
        float z1 = fmaf(bfhi(w[i]), sc[2 * i + 1], sh[2 * i + 1]);
        r.u[i] = pk2(lrelu(z0), lrelu(z1));
    }
    return r.s;
}

// ---------------------------------------------------------------------------
__global__ void detect_i32(const unsigned int* __restrict__ w, int* __restrict__ flag) {
    unsigned long long m = __ballot(w[2 * threadIdx.x + 1] != 0u);
    if (threadIdx.x == 0) *flag = (m != 0ull) ? 1 : 0;
}

// ---------------------------------------------------------------------------
// Shared epilogue: per-(b,o) sum/sumsq partials -> partials[ablk][o*2+{0,1}]
// NW = waves per block (4 for 256-thread kernels, 8 for 512-thread kernels).
template<int NW>
__device__ __forceinline__ void stats_epilogue(
        float (&sacc)[4][4], float (&s2acc)[4][4],
        int tid, int wv, int col, int quad, int ablk,
        float* __restrict__ partials) {
    __shared__ float lds[2][NW][64];
#pragma unroll
    for (int m = 0; m < 4; ++m)
#pragma unroll
        for (int r = 0; r < 4; ++r) {
            float s = sacc[m][r], s2 = s2acc[m][r];
#pragma unroll
            for (int d = 1; d < 16; d <<= 1) {
                s  += __shfl_xor(s,  d, 16);
                s2 += __shfl_xor(s2, d, 16);
            }
            if (col == 0) {
                int o = m * 16 + quad * 4 + r;
                lds[0][wv][o] = s;
                lds[1][wv][o] = s2;
            }
        }
    __syncthreads();
    if (tid < 64) {
        float s = 0.f, s2 = 0.f;
#pragma unroll
        for (int w = 0; w < NW; ++w) { s += lds[0][w][tid]; s2 += lds[1][w][tid]; }
        ((float2*)(partials + (size_t)ablk * 128))[tid] = make_float2(s, s2);
    }
}

// ---------------------------------------------------------------------------
// Layer 1: gather + concat + MFMA (K=35 padded to 64). Software-pipelined:
// edge index 2-deep, signal/ef 1-deep prefetch (clamped, always in-bounds).
// Per-wave body is EXACTLY the proven round-0 code (VGPR=56, zero spill);
// occupancy is raised via block shape only: 512 threads = 8 waves x 8 tiles
// (same 64 tiles/block, same grid/partials). At VGPR<=64 this gives 4
// blocks/CU = 32 waves/CU (was 16). NO min-waves launch bound: forcing
// (512,8) made the allocator emit VGPR=32 + full spill (5x regression),
// and runtime-indexed pipeline arrays went to scratch (2x regression).
__global__ __launch_bounds__(512) void mfma_stage1(
        const float* __restrict__ signal,   // (BN, 32)
        const void*  __restrict__ edges,
        const float* __restrict__ ef,       // (E, 3)
        const float* __restrict__ W1,       // (64, 35)
        unsigned short* __restrict__ Y,
        const int* __restrict__ flag,
        float* __restrict__ partials) {
    const int tid = threadIdx.x, lane = tid & 63, wv = tid >> 6;
    const int col = lane & 15, quad = lane >> 4;

    short8 afrag[4][2];
#pragma unroll
    for (int m = 0; m < 4; ++m) {
        const float* wr = W1 + (m * 16 + col) * 35;
        float f[8];
#pragma unroll
        for (int j = 0; j < 8; ++j) f[j] = wr[quad * 8 + j];
        afrag[m][0] = pack8(f);
#pragma unroll
        for (int j = 0; j < 8; ++j) f[j] = (quad == 0 && j < 3) ? wr[32 + j] : 0.f;
        afrag[m][1] = pack8(f);
    }
    const bool is32 = (*flag != 0);
    const int* ip = (const int*)edges;
    const long long* lp = (const long long*)edges;

    float sacc[4][4] = {{0.f}}, s2acc[4][4] = {{0.f}};
    const int tile0 = blockIdx.x * TPB + wv * TPW8;
    const int eW = tile0 * 16 + col;      // this lane's edge for tile ti: eW + 16*ti

    // pipeline preload
    long long idxA = is32 ? (long long)ip[eW] : lp[eW];
    long long idxB = is32 ? (long long)ip[min(eW + 16, E - 1)] : lp[min(eW + 16, E - 1)];
    const float* spA = signal + idxA * 32 + quad * 8;
    float4 sA0 = *(const float4*)spA;
    float4 sA1 = *(const float4*)(spA + 4);
    float efA0 = 0.f, efA1 = 0.f, efA2 = 0.f;
    if (quad == 0) {
        const float* p = ef + (size_t)eW * 3;
        efA0 = p[0]; efA1 = p[1]; efA2 = p[2];
    }

    for (int ti = 0; ti < TPW8; ++ti) {
        const int eCur = eW + ti * 16;
        // prefetch idx two ahead, signal/ef one ahead
        const int eI = min(eCur + 32, E - 1);
        long long idxC = is32 ? (long long)ip[eI] : lp[eI];
        const float* spB = signal + idxB * 32 + quad * 8;
        float4 sB0 = *(const float4*)spB;
        float4 sB1 = *(const float4*)(spB + 4);
        float efB0 = 0.f, efB1 = 0.f, efB2 = 0.f;
        if (quad == 0) {
            const float* p = ef + (size_t)min(eCur + 16, E - 1) * 3;
            efB0 = p[0]; efB1 = p[1]; efB2 = p[2];
        }
        // compute current tile from A-buffers
        float f[8] = {sA0.x, sA0.y, sA0.z, sA0.w, sA1.x, sA1.y, sA1.z, sA1.w};
        short8 b0 = pack8(f);
        float g[8] = {efA0, efA1, efA2, 0.f, 0.f, 0.f, 0.f, 0.f};
        short8 b1 = pack8(g);

        unsigned short* tp = Y + (size_t)(tile0 + ti) * 1024;
#pragma unroll
        for (int m = 0; m < 4; ++m) {
            f32x4 acc = {0.f, 0.f, 0.f, 0.f};
            acc = MFMA16(afrag[m][0], b0, acc, 0, 0, 0);
            acc = MFMA16(afrag[m][1], b1, acc, 0, 0, 0);
            *(uint2*)(tp + (m * 2 + (quad >> 1)) * 128 + col * 8 + (quad & 1) * 4) =
                make_uint2(pk2(acc[0], acc[1]), pk2(acc[2], acc[3]));
#pragma unroll
            for (int r = 0; r < 4; ++r) {
                float v = acc[r];
                sacc[m][r] += v;
                s2acc[m][r] = fmaf(v, v, s2acc[m][r]);
            }
        }
        // rotate pipeline
        sA0 = sB0; sA1 = sB1;
        efA0 = efB0; efA1 = efB1; efA2 = efB2;
        idxB = idxC;
    }
    stats_epilogue<8>(sacc, s2acc, tid, wv, col, quad, blockIdx.x, partials);
}

// ---------------------------------------------------------------------------
// Layer 2: in-place TP GEMM: Y[o] = W * lrelu(scale*Y + shift), + stats.
// dir=1 walks blocks in reverse (LLC serpentine). One-tile-deep prefetch.
// Same occupancy transform as stage1: 8 waves x 8 tiles, unconstrained
// allocator. Worst case (VGPR>64) identical residency to round-0.
__global__ __launch_bounds__(512) void mfma_stage(
        unsigned short* __restrict__ Y,         // in-place (per-tile wave-exclusive)
        const float* __restrict__ W,            // (64, 64)
        const float* __restrict__ scale,        // (B, 64)
        const float* __restrict__ shift,
        float* __restrict__ partials,
        const int dir) {
    const int tid = threadIdx.x, lane = tid & 63, wv = tid >> 6;
    const int col = lane & 15, quad = lane >> 4;
    const int ablk = dir ? (BLOCKS - 1 - blockIdx.x) : blockIdx.x;
    const int b    = ablk >> 8;                 // 256 blocks per batch

    short8 afrag[4][2];
#pragma unroll
    for (int m = 0; m < 4; ++m)
#pragma unroll
        for (int kc = 0; kc < 2; ++kc) {
            const float4* wp = (const float4*)(W + (m * 16 + col) * 64 + kc * 32 + quad * 8);
            float4 w0 = wp[0], w1 = wp[1];
            float f[8] = {w0.x, w0.y, w0.z, w0.w, w1.x, w1.y, w1.z, w1.w};
            afrag[m][kc] = pack8(f);
        }
    float sc[2][8], sh[2][8];
#pragma unroll
    for (int kc = 0; kc < 2; ++kc) {
        const int c0 = (kc * 4 + quad) * 8;
#pragma unroll
        for (int j = 0; j < 8; ++j) {
            sc[kc][j] = scale[b * COUT + c0 + j];
            sh[kc][j] = shift[b * COUT + c0 + j];
        }
    }
    float sacc[4][4] = {{0.f}}, s2acc[4][4] = {{0.f}};
    const int tile0 = ablk * TPB + wv * TPW8;
    const int off0 = quad * 128 + col * 8;

    // pipeline preload
    const unsigned short* tpA = Y + (size_t)tile0 * 1024;
    uint4 pA0 = *(const uint4*)(tpA + off0);
    uint4 pA1 = *(const uint4*)(tpA + 512 + off0);

    for (int ti = 0; ti < TPW8; ++ti) {
        // prefetch next tile (clamped: last iter re-reads own last tile, discarded)
        const unsigned short* tpB = Y + (size_t)(tile0 + min(ti + 1, TPW8 - 1)) * 1024;
        uint4 pB0 = *(const uint4*)(tpB + off0);
        uint4 pB1 = *(const uint4*)(tpB + 512 + off0);

        short8 b0 = xform(pA0, sc[0], sh[0]);
        short8 b1 = xform(pA1, sc[1], sh[1]);
        unsigned short* tp = Y + (size_t)(tile0 + ti) * 1024;
#pragma unroll
        for (int m = 0; m < 4; ++m) {
            f32x4 acc = {0.f, 0.f, 0.f, 0.f};
            acc = MFMA16(afrag[m][0], b0, acc, 0, 0, 0);
            acc = MFMA16(afrag[m][1], b1, acc, 0, 0, 0);
            *(uint2*)(tp + (m * 2 + (quad >> 1)) * 128 + col * 8 + (quad & 1) * 4) =
                make_uint2(pk2(acc[0], acc[1]), pk2(acc[2], acc[3]));
#pragma unroll
            for (int r = 0; r < 4; ++r) {
                float v = acc[r];
                sacc[m][r] += v;
                s2acc[m][r] = fmaf(v, v, s2acc[m][r]);
            }
        }
        pA0 = pB0; pA1 = pB1;
    }
    stats_epilogue<8>(sacc, s2acc, tid, wv, col, quad, ablk, partials);
}

// ---------------------------------------------------------------------------
// Layer 3 (last): GEMM without Y writeback. Per bn pair (2 tiles) tracks fp32
// max/min of pre-norm y3; per-lane values go through a WAVE-PRIVATE col-swizzled
// LDS slice (no cross-wave traffic -> no barriers), each lane then owns one
// output channel and writes the compact R record (64 mx + 64 mn floats) into
// the wave's OWN just-consumed tile 2*pr region. Race-free by program order.
// Stays at 256 threads: its 32 KB wave-private LDS caps occupancy regardless.
__global__ __launch_bounds__(256) void mfma_stage_last(
        unsigned short* __restrict__ Y,
        const float* __restrict__ W,
        const float* __restrict__ scale,
        const float* __restrict__ shift,
        float* __restrict__ partials) {
    const int tid = threadIdx.x, lane = tid & 63, wv = tid >> 6;
    const int col = lane & 15, quad = lane >> 4;
    const int ablk = blockIdx.x;
    const int b    = ablk >> 8;

    short8 afrag[4][2];
#pragma unroll
    for (int m = 0; m < 4; ++m)
#pragma unroll
        for (int kc = 0; kc < 2; ++kc) {
            const float4* wp = (const float4*)(W + (m * 16 + col) * 64 + kc * 32 + quad * 8);
            float4 w0 = wp[0], w1 = wp[1];
            float f[8] = {w0.x, w0.y, w0.z, w0.w, w1.x, w1.y, w1.z, w1.w};
            afrag[m][kc] = pack8(f);
        }
    float sc[2][8], sh[2][8];
#pragma unroll
    for (int kc = 0; kc < 2; ++kc) {
        const int c0 = (kc * 4 + quad) * 8;
#pragma unroll
        for (int j = 0; j < 8; ++j) {
            sc[kc][j] = scale[b * COUT + c0 + j];
            sh[kc][j] = shift[b * COUT + c0 + j];
        }
    }
    float sacc[4][4] = {{0.f}}, s2acc[4][4] = {{0.f}};
    const int tile0 = ablk * TPB + wv * TPW16;
    const int off0 = quad * 128 + col * 8;

    // wave-private slices: [wv][col(16)][o(64) x (mx,mn)] fp32, col-swizzled
    __shared__ float ldsP[4][2048];              // 32 KB
    float* P = ldsP[wv];
    const int swz = (col & 7) << 2;

    const unsigned short* tpA = Y + (size_t)tile0 * 1024;
    uint4 pA0 = *(const uint4*)(tpA + off0);
    uint4 pA1 = *(const uint4*)(tpA + 512 + off0);

    for (int pr = 0; pr < TPW16 / 2; ++pr) {
        float mx[4][4], mn[4][4];
#pragma unroll
        for (int m = 0; m < 4; ++m)
#pragma unroll
            for (int r = 0; r < 4; ++r) { mx[m][r] = -1e30f; mn[m][r] = 1e30f; }

#pragma unroll
        for (int hf = 0; hf < 2; ++hf) {
            const int ti = pr * 2 + hf;
            const unsigned short* tpB = Y + (size_t)(tile0 + min(ti + 1, TPW16 - 1)) * 1024;
            uint4 pB0 = *(const uint4*)(tpB + off0);
            uint4 pB1 = *(const uint4*)(tpB + 512 + off0);

            short8 b0 = xform(pA0, sc[0], sh[0]);
            short8 b1 = xform(pA1, sc[1], sh[1]);
#pragma unroll
            for (int m = 0; m < 4; ++m) {
                f32x4 acc = {0.f, 0.f, 0.f, 0.f};
                acc = MFMA16(afrag[m][0], b0, acc, 0, 0, 0);
                acc = MFMA16(afrag[m][1], b1, acc, 0, 0, 0);
#pragma unroll
                for (int r = 0; r < 4; ++r) {
                    float v = acc[r];
                    sacc[m][r] += v;
                    s2acc[m][r] = fmaf(v, v, s2acc[m][r]);
                    mx[m][r] = fmaxf(mx[m][r], v);
                    mn[m][r] = fminf(mn[m][r], v);
                }
            }
            pA0 = pB0; pA1 = pB1;
        }
        // stash per-lane (mx,mn) into the wave slice (8x ds_write_b128, 2-way max)
#pragma unroll
        for (int m = 0; m < 4; ++m) {
            const int fi0 = col * 128 + m * 32 + quad * 8;
            float4 lo = {mx[m][0], mn[m][0], mx[m][1], mn[m][1]};
            float4 hi = {mx[m][2], mn[m][2], mx[m][3], mn[m][3]};
            *(float4*)&P[fi0 ^ swz] = lo;
            *(float4*)&P[(fi0 + 4) ^ swz] = hi;
        }
        __builtin_amdgcn_wave_barrier();
        // wave-local reduce over the 16 edge-columns: lane owns channel o=lane
        float gx = -1e30f, gn = 1e30f;
#pragma unroll
        for (int cc = 0; cc < 16; ++cc) {
            const float2 v = *(const float2*)&P[(cc * 128 + lane * 2) ^ ((cc & 7) << 2)];
            gx = fmaxf(gx, v.x);
            gn = fminf(gn, v.y);
        }
        __builtin_amdgcn_wave_barrier();
        // compact R record into this wave's OWN already-read tile 2*pr region
        float* R = (float*)(Y + (size_t)(tile0 + 2 * pr) * 1024);
        R[lane]      = gx;
        R[64 + lane] = gn;
    }
    stats_epilogue<4>(sacc, s2acc, tid, wv, col, quad, ablk, partials);
}

// ---------------------------------------------------------------------------
// Parallel finalize: one block per (o,b); 256 threads sum that batch's partials.
__global__ __launch_bounds__(256) void finalize_k(
        const float* __restrict__ partials,
        const float* __restrict__ gamma,
        const float* __restrict__ beta,
        float* __restrict__ scale,
        float* __restrict__ shift) {
    const int g = blockIdx.x;        // 0..255
    const int o = g >> 2, b = g & 3;
    const int k = threadIdx.x;       // 0..255
    const float* p = partials + (size_t)(b * 256 + k) * 128 + o * 2;
    float s = p[0], s2 = p[1];
    __shared__ float red[512];
    red[k] = s; red[256 + k] = s2;
    __syncthreads();
    for (int st = 128; st > 0; st >>= 1) {
        if (k < st) { red[k] += red[k + st]; red[256 + k] += red[256 + k + st]; }
        __syncthreads();
    }
    if (k == 0) {
        const float inv_n = 1.f / (float)PERB;
        float mean = red[0] * inv_n;
        float var  = red[256] * inv_n - mean * mean;
        float inv  = rsqrtf(var + EPS);
        float scv  = gamma[o] * inv;
        scale[b * COUT + o] = scv;
        shift[b * COUT + o] = beta[o] - mean * scv;
    }
}

// ---------------------------------------------------------------------------
// Final pool: read compact R records (fp32 max/min of pre-norm y3) from the
// per-(wv,pr) slots inside Y, apply affine norm (sign-aware), one lrelu.
__global__ __launch_bounds__(256) void pool_final(
        const unsigned short* __restrict__ Y,
        const float* __restrict__ scale,
        const float* __restrict__ shift,
        float* __restrict__ out) {
    const int t  = blockIdx.x * 256 + threadIdx.x;   // 0..262143
    const int og = t & 7;
    const int bn = t >> 3;
    const int b  = bn >> 13;
    const int ablk = bn >> 5;
    const int wv   = (bn >> 3) & 3;
    const int pr   = bn & 7;
    const float* base =
        (const float*)(Y + (size_t)(ablk * TPB + wv * TPW16 + 2 * pr) * 1024);
    float4 x0 = *(const float4*)(base + og * 8);
    float4 x1 = *(const float4*)(base + og * 8 + 4);
    float4 n0 = *(const float4*)(base + 64 + og * 8);
    float4 n1 = *(const float4*)(base + 68 + og * 8);
    float mxv[8] = {x0.x, x0.y, x0.z, x0.w, x1.x, x1.y, x1.z, x1.w};
    float mnv[8] = {n0.x, n0.y, n0.z, n0.w, n1.x, n1.y, n1.z, n1.w};
    float r[8];
#pragma unroll
    for (int j = 0; j < 8; ++j) {
        const int o = og * 8 + j;
        const float s = scale[b * COUT + o], h = shift[b * COUT + o];
        float m = (s >= 0.f ? mxv[j] : mnv[j]) * s + h;
        r[j] = lrelu(m);
    }
    float4* q = (float4*)(out + (size_t)bn * COUT + og * 8);
    q[0] = make_float4(r[0], r[1], r[2], r[3]);
    q[1] = make_float4(r[4], r[5], r[6], r[7]);
}

// ---------------------------------------------------------------------------
extern "C" void kernel_launch(void* const* d_in, const int* in_sizes, int n_in,
                              void* d_out, int out_size, void* d_ws, size_t ws_size,
                              hipStream_t stream) {
    const float* signal = (const float*)d_in[0];
    const void*  edges  = d_in[1];
    const float* ef     = (const float*)d_in[2];
    const float* W1 = (const float*)d_in[4];
    const float* g1 = (const float*)d_in[5];
    const float* b1 = (const float*)d_in[6];
    const float* W2 = (const float*)d_in[7];
    const float* g2 = (const float*)d_in[8];
    const float* b2 = (const float*)d_in[9];
    const float* W3 = (const float*)d_in[10];
    const float* g3 = (const float*)d_in[11];
    const float* b3 = (const float*)d_in[12];
    float* out = (float*)d_out;

    // Workspace: Y (134.2 MB) + partials (512 KB) + flag + 6x256 scale/shift
    unsigned short* Y = (unsigned short*)d_ws;
    const size_t YB = (size_t)E * COUT * sizeof(unsigned short);
    float* partials = (float*)((char*)d_ws + YB);
    char*  tail = (char*)d_ws + YB + (size_t)BLOCKS * 128 * sizeof(float);
    int*   flag = (int*)tail;
    float* ss   = (float*)(tail + 256);
    float *sc0 = ss,        *sh0 = ss + 256;
    float *sc1 = ss + 512,  *sh1 = ss + 768;
    float *sc2 = ss + 1024, *sh2 = ss + 1280;

    detect_i32<<<1, 64, 0, stream>>>((const unsigned int*)edges, flag);

    mfma_stage1<<<BLOCKS, 512, 0, stream>>>(signal, edges, ef, W1, Y, flag, partials);
    finalize_k<<<256, 256, 0, stream>>>(partials, g1, b1, sc0, sh0);

    mfma_stage<<<BLOCKS, 512, 0, stream>>>(Y, W2, sc0, sh0, partials, 1);
    finalize_k<<<256, 256, 0, stream>>>(partials, g2, b2, sc1, sh1);

    mfma_stage_last<<<BLOCKS, 256, 0, stream>>>(Y, W3, sc1, sh1, partials);
    finalize_k<<<256, 256, 0, stream>>>(partials, g3, b3, sc2, sh2);

    pool_final<<<1024, 256, 0, stream>>>(Y, sc2, sh2, out);
}

// Round 4
// 168.706 us; speedup vs baseline: 3.7852x; 1.1514x over previous
//
#include <hip/hip_runtime.h>
#include <hip/hip_bf16.h>
#include <math.h>

// Problem constants (fixed by setup_inputs)
constexpr int B    = 4;
constexpr int N    = 8192;
constexpr int COUT = 64;
constexpr int E    = B * N * 32;      // 1048576 edges
constexpr int PERB = N * 32;          // 262144 elements per (b,o) norm group
constexpr int TILES  = E / 16;        // 65536 16-edge tiles

// Stage1/stage2 blocking: 256 thr = 4 waves x TPW=8 tiles -> 32 tiles/block,
// 2048 blocks (8192 waves = 32/CU potential at VGPR<=64).
constexpr int TPW    = 8;
constexpr int TPB    = TPW * 4;        // 32 tiles/block
constexpr int BLK12  = TILES / TPB;    // 2048 (512 per batch)
// Stage3/pool blocking (unchanged from the proven 159us config).
constexpr int TPW_L  = 16;
constexpr int TPB_L  = TPW_L * 4;      // 64 tiles/block
constexpr int BLK_L  = TILES / TPB_L;  // 1024 (256 per batch)
constexpr float EPS   = 1e-5f;
constexpr float SLOPE = 0.1f;

// Tiled-pack activation layout (bf16):
//   addr(c, e) = (e>>4)*1024 + (c>>3)*128 + (e&15)*8 + (c&7)    [ushort units]
// -> MFMA B-frag (8 ch of one edge) = one 16B load; C-store = 8B per m-tile.

typedef __attribute__((ext_vector_type(8))) short short8;
typedef __attribute__((ext_vector_type(4))) float f32x4;
#define MFMA16 __builtin_amdgcn_mfma_f32_16x16x32_bf16

union S8 { short8 s; unsigned int u[4]; };

__device__ __forceinline__ float bflo(unsigned int u) {
    union { unsigned int x; float f; } v; v.x = u << 16; return v.f;
}
__device__ __forceinline__ float bfhi(unsigned int u) {
    union { unsigned int x; float f; } v; v.x = u & 0xFFFF0000u; return v.f;
}
// packed f32x2 -> bf16x2 (RTNE); low 16 bits = a
__device__ __forceinline__ unsigned int pk2(float a, float b) {
    union { __hip_bfloat162 h; unsigned int u; } v;
    v.h = __float22bfloat162_rn(make_float2(a, b));
    return v.u;
}
__device__ __forceinline__ float lrelu(float z) {
    return fmaxf(z, SLOPE * z);
}
__device__ __forceinline__ short8 pack8(const float* f) {
    S8 r;
#pragma unroll
    for (int i = 0; i < 4; ++i) r.u[i] = pk2(f[2 * i], f[2 * i + 1]);
    return r.s;
}
// unpack 8 bf16, apply per-channel scale/shift + leaky relu, repack bf16
__device__ __forceinline__ short8 xform(uint4 raw, const float* sc, const float* sh) {
    unsigned int w[4] = {raw.x, raw.y, raw.z, raw.w};
    S8 r;
#pragma unroll
    for (int i = 0; i < 4; ++i) {
        float z0 = fmaf(bflo(w[i]), sc[2 * i],     sh[2 * i]);
        float z1 = fmaf(bfhi(w[i]), sc[2 * i + 1], sh[2 * i + 1]);
        r.u[i] = pk2(lrelu(z0), lrelu(z1));
    }
    return r.s;
}

// ---------------------------------------------------------------------------
__global__ void detect_i32(const unsigned int* __restrict__ w, int* __restrict__ flag) {
    unsigned long long m = __ballot(w[2 * threadIdx.x + 1] != 0u);
    if (threadIdx.x == 0) *flag = (m != 0ull) ? 1 : 0;
}

// ---------------------------------------------------------------------------
// Shared epilogue: per-(b,o) sum/sumsq partials -> partials[ablk][o*2+{0,1}]
__device__ __forceinline__ void stats_epilogue(
        float (&sacc)[4][4], float (&s2acc)[4][4],
        int tid, int wv, int col, int quad, int ablk,
        float* __restrict__ partials) {
    __shared__ float lds[2][4][64];
#pragma unroll
    for (int m = 0; m < 4; ++m)
#pragma unroll
        for (int r = 0; r < 4; ++r) {
            float s = sacc[m][r], s2 = s2acc[m][r];
#pragma unroll
            for (int d = 1; d < 16; d <<= 1) {
                s  += __shfl_xor(s,  d, 16);
                s2 += __shfl_xor(s2, d, 16);
            }
            if (col == 0) {
                int o = m * 16 + quad * 4 + r;
                lds[0][wv][o] = s;
                lds[1][wv][o] = s2;
            }
        }
    __syncthreads();
    if (tid < 64) {
        float s  = lds[0][0][tid] + lds[0][1][tid] + lds[0][2][tid] + lds[0][3][tid];
        float s2 = lds[1][0][tid] + lds[1][1][tid] + lds[1][2][tid] + lds[1][3][tid];
        ((float2*)(partials + (size_t)ablk * 128))[tid] = make_float2(s, s2);
    }
}

// ---------------------------------------------------------------------------
// Layer 1: gather + concat + MFMA (K=35 padded to 64). Software-pipelined:
// edge index 2-deep, signal/ef 1-deep prefetch (clamped, always in-bounds).
// Per-wave body is byte-identical to the proven round-0 code (VGPR=56);
// occupancy is doubled via GRID ONLY: 2048 blocks x 4 waves x 8 tiles
// (32 waves/CU potential at VGPR<=64; 8 blocks/CU). Block shape stays
// 256 threads -- 512-thread shape made VGPR creep to 88 (cliff, 1.5x slower),
// forced (512,8) bound spilled (5x), runtime-indexed arrays went to scratch
// (2x). #pragma unroll 1 pins the trip-8 loop to round-0 codegen.
__global__ __launch_bounds__(256) void mfma_stage1(
        const float* __restrict__ signal,   // (BN, 32)
        const void*  __restrict__ edges,
        const float* __restrict__ ef,       // (E, 3)
        const float* __restrict__ W1,       // (64, 35)
        unsigned short* __restrict__ Y,
        const int* __restrict__ flag,
        float* __restrict__ partials) {
    const int tid = threadIdx.x, lane = tid & 63, wv = tid >> 6;
    const int col = lane & 15, quad = lane >> 4;

    short8 afrag[4][2];
#pragma unroll
    for (int m = 0; m < 4; ++m) {
        const float* wr = W1 + (m * 16 + col) * 35;
        float f[8];
#pragma unroll
        for (int j = 0; j < 8; ++j) f[j] = wr[quad * 8 + j];
        afrag[m][0] = pack8(f);
#pragma unroll
        for (int j = 0; j < 8; ++j) f[j] = (quad == 0 && j < 3) ? wr[32 + j] : 0.f;
        afrag[m][1] = pack8(f);
    }
    const bool is32 = (*flag != 0);
    const int* ip = (const int*)edges;
    const long long* lp = (const long long*)edges;

    float sacc[4][4] = {{0.f}}, s2acc[4][4] = {{0.f}};
    const int tile0 = blockIdx.x * TPB + wv * TPW;
    const int eW = tile0 * 16 + col;      // this lane's edge for tile ti: eW + 16*ti

    // pipeline preload
    long long idxA = is32 ? (long long)ip[eW] : lp[eW];
    long long idxB = is32 ? (long long)ip[min(eW + 16, E - 1)] : lp[min(eW + 16, E - 1)];
    const float* spA = signal + idxA * 32 + quad * 8;
    float4 sA0 = *(const float4*)spA;
    float4 sA1 = *(const float4*)(spA + 4);
    float efA0 = 0.f, efA1 = 0.f, efA2 = 0.f;
    if (quad == 0) {
        const float* p = ef + (size_t)eW * 3;
        efA0 = p[0]; efA1 = p[1]; efA2 = p[2];
    }

#pragma unroll 1
    for (int ti = 0; ti < TPW; ++ti) {
        const int eCur = eW + ti * 16;
        // prefetch idx two ahead, signal/ef one ahead
        const int eI = min(eCur + 32, E - 1);
        long long idxC = is32 ? (long long)ip[eI] : lp[eI];
        const float* spB = signal + idxB * 32 + quad * 8;
        float4 sB0 = *(const float4*)spB;
        float4 sB1 = *(const float4*)(spB + 4);
        float efB0 = 0.f, efB1 = 0.f, efB2 = 0.f;
        if (quad == 0) {
            const float* p = ef + (size_t)min(eCur + 16, E - 1) * 3;
            efB0 = p[0]; efB1 = p[1]; efB2 = p[2];
        }
        // compute current tile from A-buffers
        float f[8] = {sA0.x, sA0.y, sA0.z, sA0.w, sA1.x, sA1.y, sA1.z, sA1.w};
        short8 b0 = pack8(f);
        float g[8] = {efA0, efA1, efA2, 0.f, 0.f, 0.f, 0.f, 0.f};
        short8 b1 = pack8(g);

        unsigned short* tp = Y + (size_t)(tile0 + ti) * 1024;
#pragma unroll
        for (int m = 0; m < 4; ++m) {
            f32x4 acc = {0.f, 0.f, 0.f, 0.f};
            acc = MFMA16(afrag[m][0], b0, acc, 0, 0, 0);
            acc = MFMA16(afrag[m][1], b1, acc, 0, 0, 0);
            *(uint2*)(tp + (m * 2 + (quad >> 1)) * 128 + col * 8 + (quad & 1) * 4) =
                make_uint2(pk2(acc[0], acc[1]), pk2(acc[2], acc[3]));
#pragma unroll
            for (int r = 0; r < 4; ++r) {
                float v = acc[r];
                sacc[m][r] += v;
                s2acc[m][r] = fmaf(v, v, s2acc[m][r]);
            }
        }
        // rotate pipeline
        sA0 = sB0; sA1 = sB1;
        efA0 = efB0; efA1 = efB1; efA2 = efB2;
        idxB = idxC;
    }
    stats_epilogue(sacc, s2acc, tid, wv, col, quad, blockIdx.x, partials);
}

// ---------------------------------------------------------------------------
// Layer 2: in-place TP GEMM: Y[o] = W * lrelu(scale*Y + shift), + stats.
// dir=1 walks blocks in reverse (LLC serpentine). One-tile-deep prefetch.
// Same grid-doubling transform as stage1 (2048 blocks, TPW=8, unroll 1).
__global__ __launch_bounds__(256) void mfma_stage(
        unsigned short* __restrict__ Y,         // in-place (per-tile wave-exclusive)
        const float* __restrict__ W,            // (64, 64)
        const float* __restrict__ scale,        // (B, 64)
        const float* __restrict__ shift,
        float* __restrict__ partials,
        const int dir) {
    const int tid = threadIdx.x, lane = tid & 63, wv = tid >> 6;
    const int col = lane & 15, quad = lane >> 4;
    const int ablk = dir ? (BLK12 - 1 - blockIdx.x) : blockIdx.x;
    const int b    = ablk >> 9;                 // 512 blocks per batch

    short8 afrag[4][2];
#pragma unroll
    for (int m = 0; m < 4; ++m)
#pragma unroll
        for (int kc = 0; kc < 2; ++kc) {
            const float4* wp = (const float4*)(W + (m * 16 + col) * 64 + kc * 32 + quad * 8);
            float4 w0 = wp[0], w1 = wp[1];
            float f[8] = {w0.x, w0.y, w0.z, w0.w, w1.x, w1.y, w1.z, w1.w};
            afrag[m][kc] = pack8(f);
        }
    float sc[2][8], sh[2][8];
#pragma unroll
    for (int kc = 0; kc < 2; ++kc) {
        const int c0 = (kc * 4 + quad) * 8;
#pragma unroll
        for (int j = 0; j < 8; ++j) {
            sc[kc][j] = scale[b * COUT + c0 + j];
            sh[kc][j] = shift[b * COUT + c0 + j];
        }
    }
    float sacc[4][4] = {{0.f}}, s2acc[4][4] = {{0.f}};
    const int tile0 = ablk * TPB + wv * TPW;
    const int off0 = quad * 128 + col * 8;

    // pipeline preload
    const unsigned short* tpA = Y + (size_t)tile0 * 1024;
    uint4 pA0 = *(const uint4*)(tpA + off0);
    uint4 pA1 = *(const uint4*)(tpA + 512 + off0);

#pragma unroll 1
    for (int ti = 0; ti < TPW; ++ti) {
        // prefetch next tile (clamped: last iter re-reads own last tile, discarded)
        const unsigned short* tpB = Y + (size_t)(tile0 + min(ti + 1, TPW - 1)) * 1024;
        uint4 pB0 = *(const uint4*)(tpB + off0);
        uint4 pB1 = *(const uint4*)(tpB + 512 + off0);

        short8 b0 = xform(pA0, sc[0], sh[0]);
        short8 b1 = xform(pA1, sc[1], sh[1]);
        unsigned short* tp = Y + (size_t)(tile0 + ti) * 1024;
#pragma unroll
        for (int m = 0; m < 4; ++m) {
            f32x4 acc = {0.f, 0.f, 0.f, 0.f};
            acc = MFMA16(afrag[m][0], b0, acc, 0, 0, 0);
            acc = MFMA16(afrag[m][1], b1, acc, 0, 0, 0);
            *(uint2*)(tp + (m * 2 + (quad >> 1)) * 128 + col * 8 + (quad & 1) * 4) =
                make_uint2(pk2(acc[0], acc[1]), pk2(acc[2], acc[3]));
#pragma unroll
            for (int r = 0; r < 4; ++r) {
                float v = acc[r];
                sacc[m][r] += v;
                s2acc[m][r] = fmaf(v, v, s2acc[m][r]);
            }
        }
        pA0 = pB0; pA1 = pB1;
    }
    stats_epilogue(sacc, s2acc, tid, wv, col, quad, ablk, partials);
}

// ---------------------------------------------------------------------------
// Layer 3 (last): GEMM without Y writeback. Per bn pair (2 tiles) tracks fp32
// max/min of pre-norm y3; per-lane values go through a WAVE-PRIVATE col-swizzled
// LDS slice (no cross-wave traffic -> no barriers), each lane then owns one
// output channel and writes the compact R record (64 mx + 64 mn floats) into
// the wave's OWN just-consumed tile 2*pr region. Race-free by program order.
// UNCHANGED from the proven config (1024 blocks, TPB_L=64, TPW_L=16): its
// 32 KB wave-private LDS caps occupancy regardless of grid shape.
__global__ __launch_bounds__(256) void mfma_stage_last(
        unsigned short* __restrict__ Y,
        const float* __restrict__ W,
        const float* __restrict__ scale,
        const float* __restrict__ shift,
        float* __restrict__ partials) {
    const int tid = threadIdx.x, lane = tid & 63, wv = tid >> 6;
    const int col = lane & 15, quad = lane >> 4;
    const int ablk = blockIdx.x;
    const int b    = ablk >> 8;                 // 256 blocks per batch

    short8 afrag[4][2];
#pragma unroll
    for (int m = 0; m < 4; ++m)
#pragma unroll
        for (int kc = 0; kc < 2; ++kc) {
            const float4* wp = (const float4*)(W + (m * 16 + col) * 64 + kc * 32 + quad * 8);
            float4 w0 = wp[0], w1 = wp[1];
            float f[8] = {w0.x, w0.y, w0.z, w0.w, w1.x, w1.y, w1.z, w1.w};
            afrag[m][kc] = pack8(f);
        }
    float sc[2][8], sh[2][8];
#pragma unroll
    for (int kc = 0; kc < 2; ++kc) {
        const int c0 = (kc * 4 + quad) * 8;
#pragma unroll
        for (int j = 0; j < 8; ++j) {
            sc[kc][j] = scale[b * COUT + c0 + j];
            sh[kc][j] = shift[b * COUT + c0 + j];
        }
    }
    float sacc[4][4] = {{0.f}}, s2acc[4][4] = {{0.f}};
    const int tile0 = ablk * TPB_L + wv * TPW_L;
    const int off0 = quad * 128 + col * 8;

    // wave-private slices: [wv][col(16)][o(64) x (mx,mn)] fp32, col-swizzled
    __shared__ float ldsP[4][2048];              // 32 KB
    float* P = ldsP[wv];
    const int swz = (col & 7) << 2;

    const unsigned short* tpA = Y + (size_t)tile0 * 1024;
    uint4 pA0 = *(const uint4*)(tpA + off0);
    uint4 pA1 = *(const uint4*)(tpA + 512 + off0);

    for (int pr = 0; pr < TPW_L / 2; ++pr) {
        float mx[4][4], mn[4][4];
#pragma unroll
        for (int m = 0; m < 4; ++m)
#pragma unroll
            for (int r = 0; r < 4; ++r) { mx[m][r] = -1e30f; mn[m][r] = 1e30f; }

#pragma unroll
        for (int hf = 0; hf < 2; ++hf) {
            const int ti = pr * 2 + hf;
            const unsigned short* tpB = Y + (size_t)(tile0 + min(ti + 1, TPW_L - 1)) * 1024;
            uint4 pB0 = *(const uint4*)(tpB + off0);
            uint4 pB1 = *(const uint4*)(tpB + 512 + off0);

            short8 b0 = xform(pA0, sc[0], sh[0]);
            short8 b1 = xform(pA1, sc[1], sh[1]);
#pragma unroll
            for (int m = 0; m < 4; ++m) {
                f32x4 acc = {0.f, 0.f, 0.f, 0.f};
                acc = MFMA16(afrag[m][0], b0, acc, 0, 0, 0);
                acc = MFMA16(afrag[m][1], b1, acc, 0, 0, 0);
#pragma unroll
                for (int r = 0; r < 4; ++r) {
                    float v = acc[r];
                    sacc[m][r] += v;
                    s2acc[m][r] = fmaf(v, v, s2acc[m][r]);
                    mx[m][r] = fmaxf(mx[m][r], v);
                    mn[m][r] = fminf(mn[m][r], v);
                }
            }
            pA0 = pB0; pA1 = pB1;
        }
        // stash per-lane (mx,mn) into the wave slice (8x ds_write_b128, 2-way max)
#pragma unroll
        for (int m = 0; m < 4; ++m) {
            const int fi0 = col * 128 + m * 32 + quad * 8;
            float4 lo = {mx[m][0], mn[m][0], mx[m][1], mn[m][1]};
            float4 hi = {mx[m][2], mn[m][2], mx[m][3], mn[m][3]};
            *(float4*)&P[fi0 ^ swz] = lo;
            *(float4*)&P[(fi0 + 4) ^ swz] = hi;
        }
        __builtin_amdgcn_wave_barrier();
        // wave-local reduce over the 16 edge-columns: lane owns channel o=lane
        float gx = -1e30f, gn = 1e30f;
#pragma unroll
        for (int cc = 0; cc < 16; ++cc) {
            const float2 v = *(const float2*)&P[(cc * 128 + lane * 2) ^ ((cc & 7) << 2)];
            gx = fmaxf(gx, v.x);
            gn = fminf(gn, v.y);
        }
        __builtin_amdgcn_wave_barrier();
        // compact R record into this wave's OWN already-read tile 2*pr region
        float* R = (float*)(Y + (size_t)(tile0 + 2 * pr) * 1024);
        R[lane]      = gx;
        R[64 + lane] = gn;
    }
    stats_epilogue(sacc, s2acc, tid, wv, col, quad, ablk, partials);
}

// ---------------------------------------------------------------------------
// Parallel finalize: one block per (o,b); 256 threads sum that batch's
// partials. KB = partial-blocks per batch (512 for stages 1-2, 256 for 3).
__global__ __launch_bounds__(256) void finalize_k(
        const float* __restrict__ partials,
        const float* __restrict__ gamma,
        const float* __restrict__ beta,
        float* __restrict__ scale,
        float* __restrict__ shift,
        const int KB) {
    const int g = blockIdx.x;        // 0..255
    const int o = g >> 2, b = g & 3;
    const int k = threadIdx.x;       // 0..255
    float s = 0.f, s2 = 0.f;
    for (int q = k; q < KB; q += 256) {
        const float* p = partials + (size_t)(b * KB + q) * 128 + o * 2;
        s += p[0]; s2 += p[1];
    }
    __shared__ float red[512];
    red[k] = s; red[256 + k] = s2;
    __syncthreads();
    for (int st = 128; st > 0; st >>= 1) {
        if (k < st) { red[k] += red[k + st]; red[256 + k] += red[256 + k + st]; }
        __syncthreads();
    }
    if (k == 0) {
        const float inv_n = 1.f / (float)PERB;
        float mean = red[0] * inv_n;
        float var  = red[256] * inv_n - mean * mean;
        float inv  = rsqrtf(var + EPS);
        float scv  = gamma[o] * inv;
        scale[b * COUT + o] = scv;
        shift[b * COUT + o] = beta[o] - mean * scv;
    }
}

// ---------------------------------------------------------------------------
// Final pool: read compact R records (fp32 max/min of pre-norm y3) from the
// per-(wv,pr) slots inside Y, apply affine norm (sign-aware), one lrelu.
// Layout matches mfma_stage_last (TPB_L/TPW_L) -- unchanged.
__global__ __launch_bounds__(256) void pool_final(
        const unsigned short* __restrict__ Y,
        const float* __restrict__ scale,
        const float* __restrict__ shift,
        float* __restrict__ out) {
    const int t  = blockIdx.x * 256 + threadIdx.x;   // 0..262143
    const int og = t & 7;
    const int bn = t >> 3;
    const int b  = bn >> 13;
    const int ablk = bn >> 5;
    const int wv   = (bn >> 3) & 3;
    const int pr   = bn & 7;
    const float* base =
        (const float*)(Y + (size_t)(ablk * TPB_L + wv * TPW_L + 2 * pr) * 1024);
    float4 x0 = *(const float4*)(base + og * 8);
    float4 x1 = *(const float4*)(base + og * 8 + 4);
    float4 n0 = *(const float4*)(base + 64 + og * 8);
    float4 n1 = *(const float4*)(base + 68 + og * 8);
    float mxv[8] = {x0.x, x0.y, x0.z, x0.w, x1.x, x1.y, x1.z, x1.w};
    float mnv[8] = {n0.x, n0.y, n0.z, n0.w, n1.x, n1.y, n1.z, n1.w};
    float r[8];
#pragma unroll
    for (int j = 0; j < 8; ++j) {
        const int o = og * 8 + j;
        const float s = scale[b * COUT + o], h = shift[b * COUT + o];
        float m = (s >= 0.f ? mxv[j] : mnv[j]) * s + h;
        r[j] = lrelu(m);
    }
    float4* q = (float4*)(out + (size_t)bn * COUT + og * 8);
    q[0] = make_float4(r[0], r[1], r[2], r[3]);
    q[1] = make_float4(r[4], r[5], r[6], r[7]);
}

// ---------------------------------------------------------------------------
extern "C" void kernel_launch(void* const* d_in, const int* in_sizes, int n_in,
                              void* d_out, int out_size, void* d_ws, size_t ws_size,
                              hipStream_t stream) {
    const float* signal = (const float*)d_in[0];
    const void*  edges  = d_in[1];
    const float* ef     = (const float*)d_in[2];
    const float* W1 = (const float*)d_in[4];
    const float* g1 = (const float*)d_in[5];
    const float* b1 = (const float*)d_in[6];
    const float* W2 = (const float*)d_in[7];
    const float* g2 = (const float*)d_in[8];
    const float* b2 = (const float*)d_in[9];
    const float* W3 = (const float*)d_in[10];
    const float* g3 = (const float*)d_in[11];
    const float* b3 = (const float*)d_in[12];
    float* out = (float*)d_out;

    // Workspace: Y (134.2 MB) + partials (1 MB) + flag + 6x256 scale/shift
    unsigned short* Y = (unsigned short*)d_ws;
    const size_t YB = (size_t)E * COUT * sizeof(unsigned short);
    float* partials = (float*)((char*)d_ws + YB);
    char*  tail = (char*)d_ws + YB + (size_t)BLK12 * 128 * sizeof(float);
    int*   flag = (int*)tail;
    float* ss   = (float*)(tail + 256);
    float *sc0 = ss,        *sh0 = ss + 256;
    float *sc1 = ss + 512,  *sh1 = ss + 768;
    float *sc2 = ss + 1024, *sh2 = ss + 1280;

    detect_i32<<<1, 64, 0, stream>>>((const unsigned int*)edges, flag);

    mfma_stage1<<<BLK12, 256, 0, stream>>>(signal, edges, ef, W1, Y, flag, partials);
    finalize_k<<<256, 256, 0, stream>>>(partials, g1, b1, sc0, sh0, 512);

    mfma_stage<<<BLK12, 256, 0, stream>>>(Y, W2, sc0, sh0, partials, 1);
    finalize_k<<<256, 256, 0, stream>>>(partials, g2, b2, sc1, sh1, 512);

    mfma_stage_last<<<BLK_L, 256, 0, stream>>>(Y, W3, sc1, sh1, partials);
    finalize_k<<<256, 256, 0, stream>>>(partials, g3, b3, sc2, sh2, 256);

    pool_final<<<1024, 256, 0, stream>>>(Y, sc2, sh2, out);
}

// Round 6
// 166.068 us; speedup vs baseline: 3.8454x; 1.0159x over previous
//
#include <hip/hip_runtime.h>
#include <hip/hip_bf16.h>
#include <math.h>

// Problem constants (fixed by setup_inputs)
constexpr int B    = 4;
constexpr int N    = 8192;
constexpr int COUT = 64;
constexpr int E    = B * N * 32;      // 1048576 edges
constexpr int PERB = N * 32;          // 262144 elements per (b,o) norm group
constexpr int TILES  = E / 16;        // 65536 16-edge tiles
constexpr int TPW    = 16;            // tiles per wave
constexpr int TPB    = TPW * 4;       // 64 tiles per block
constexpr int BLOCKS = TILES / TPB;   // 1024 (256 per batch)
constexpr float EPS   = 1e-5f;
constexpr float SLOPE = 0.1f;

// Tiled-pack activation layout (bf16):
//   addr(c, e) = (e>>4)*1024 + (c>>3)*128 + (e&15)*8 + (c&7)    [ushort units]
// -> MFMA B-frag (8 ch of one edge) = one 16B load; C-store = 8B per m-tile.

typedef __attribute__((ext_vector_type(8))) short short8;
typedef __attribute__((ext_vector_type(4))) float f32x4;
#define MFMA16 __builtin_amdgcn_mfma_f32_16x16x32_bf16

union S8 { short8 s; unsigned int u[4]; };

__device__ __forceinline__ float bflo(unsigned int u) {
    union { unsigned int x; float f; } v; v.x = u << 16; return v.f;
}
__device__ __forceinline__ float bfhi(unsigned int u) {
    union { unsigned int x; float f; } v; v.x = u & 0xFFFF0000u; return v.f;
}
// packed f32x2 -> bf16x2 (RTNE); low 16 bits = a
__device__ __forceinline__ unsigned int pk2(float a, float b) {
    union { __hip_bfloat162 h; unsigned int u; } v;
    v.h = __float22bfloat162_rn(make_float2(a, b));
    return v.u;
}
__device__ __forceinline__ float lrelu(float z) {
    return fmaxf(z, SLOPE * z);
}
__device__ __forceinline__ short8 pack8(const float* f) {
    S8 r;
#pragma unroll
    for (int i = 0; i < 4; ++i) r.u[i] = pk2(f[2 * i], f[2 * i + 1]);
    return r.s;
}
// unpack 8 bf16, apply per-channel scale/shift + leaky relu, repack bf16
__device__ __forceinline__ short8 xform(uint4 raw, const float* sc, const float* sh) {
    unsigned int w[4] = {raw.x, raw.y, raw.z, raw.w};
    S8 r;
#pragma unroll
    for (int i = 0; i < 4; ++i) {
        float z0 = fmaf(bflo(w[i]), sc[2 * i],     sh[2 * i]);
        float z1 = fmaf(bfhi(w[i]), sc[2 * i + 1], sh[2 * i + 1]);
        r.u[i] = pk2(lrelu(z0), lrelu(z1));
    }
    return r.s;
}

// ---------------------------------------------------------------------------
__global__ void detect_i32(const unsigned int* __restrict__ w, int* __restrict__ flag) {
    unsigned long long m = __ballot(w[2 * threadIdx.x + 1] != 0u);
    if (threadIdx.x == 0) *flag = (m != 0ull) ? 1 : 0;
}

// ---------------------------------------------------------------------------
// Shared epilogue: per-(b,o) sum/sumsq partials -> partials[ablk][o*2+{0,1}]
__device__ __forceinline__ void stats_epilogue(
        float (&sacc)[4][4], float (&s2acc)[4][4],
        int tid, int wv, int col, int quad, int ablk,
        float* __restrict__ partials) {
    __shared__ float lds[2][4][64];
#pragma unroll
    for (int m = 0; m < 4; ++m)
#pragma unroll
        for (int r = 0; r < 4; ++r) {
            float s = sacc[m][r], s2 = s2acc[m][r];
#pragma unroll
            for (int d = 1; d < 16; d <<= 1) {
                s  += __shfl_xor(s,  d, 16);
                s2 += __shfl_xor(s2, d, 16);
            }
            if (col == 0) {
                int o = m * 16 + quad * 4 + r;
                lds[0][wv][o] = s;
                lds[1][wv][o] = s2;
            }
        }
    __syncthreads();
    if (tid < 64) {
        float s  = lds[0][0][tid] + lds[0][1][tid] + lds[0][2][tid] + lds[0][3][tid];
        float s2 = lds[1][0][tid] + lds[1][1][tid] + lds[1][2][tid] + lds[1][3][tid];
        ((float2*)(partials + (size_t)ablk * 128))[tid] = make_float2(s, s2);
    }
}

// ---------------------------------------------------------------------------
// Layer 1: gather + concat + MFMA (K=35 padded to 64). Software-pipelined:
// edge index 2-deep, signal/ef 1-deep prefetch (clamped, always in-bounds).
// EXACT round-0 code (VGPR=56, 58us). Occupancy levers are exhausted: grid
// doubling, 512-thr blocks, forced bounds, deeper ILP all measured neutral
// or negative (r1-r4) -- resident waves pin at ~12/CU regardless.
__global__ __launch_bounds__(256) void mfma_stage1(
        const float* __restrict__ signal,   // (BN, 32)
        const void*  __restrict__ edges,
        const float* __restrict__ ef,       // (E, 3)
        const float* __restrict__ W1,       // (64, 35)
        unsigned short* __restrict__ Y,
        const int* __restrict__ flag,
        float* __restrict__ partials) {
    const int tid = threadIdx.x, lane = tid & 63, wv = tid >> 6;
    const int col = lane & 15, quad = lane >> 4;

    short8 afrag[4][2];
#pragma unroll
    for (int m = 0; m < 4; ++m) {
        const float* wr = W1 + (m * 16 + col) * 35;
        float f[8];
#pragma unroll
        for (int j = 0; j < 8; ++j) f[j] = wr[quad * 8 + j];
        afrag[m][0] = pack8(f);
#pragma unroll
        for (int j = 0; j < 8; ++j) f[j] = (quad == 0 && j < 3) ? wr[32 + j] : 0.f;
        afrag[m][1] = pack8(f);
    }
    const bool is32 = (*flag != 0);
    const int* ip = (const int*)edges;
    const long long* lp = (const long long*)edges;

    float sacc[4][4] = {{0.f}}, s2acc[4][4] = {{0.f}};
    const int tile0 = blockIdx.x * TPB + wv * TPW;
    const int eW = tile0 * 16 + col;      // this lane's edge for tile ti: eW + 16*ti

    // pipeline preload
    long long idxA = is32 ? (long long)ip[eW] : lp[eW];
    long long idxB = is32 ? (long long)ip[min(eW + 16, E - 1)] : lp[min(eW + 16, E - 1)];
    const float* spA = signal + idxA * 32 + quad * 8;
    float4 sA0 = *(const float4*)spA;
    float4 sA1 = *(const float4*)(spA + 4);
    float efA0 = 0.f, efA1 = 0.f, efA2 = 0.f;
    if (quad == 0) {
        const float* p = ef + (size_t)eW * 3;
        efA0 = p[0]; efA1 = p[1]; efA2 = p[2];
    }

    for (int ti = 0; ti < TPW; ++ti) {
        const int eCur = eW + ti * 16;
        // prefetch idx two ahead, signal/ef one ahead
        const int eI = min(eCur + 32, E - 1);
        long long idxC = is32 ? (long long)ip[eI] : lp[eI];
        const float* spB = signal + idxB * 32 + quad * 8;
        float4 sB0 = *(const float4*)spB;
        float4 sB1 = *(const float4*)(spB + 4);
        float efB0 = 0.f, efB1 = 0.f, efB2 = 0.f;
        if (quad == 0) {
            const float* p = ef + (size_t)min(eCur + 16, E - 1) * 3;
            efB0 = p[0]; efB1 = p[1]; efB2 = p[2];
        }
        // compute current tile from A-buffers
        float f[8] = {sA0.x, sA0.y, sA0.z, sA0.w, sA1.x, sA1.y, sA1.z, sA1.w};
        short8 b0 = pack8(f);
        float g[8] = {efA0, efA1, efA2, 0.f, 0.f, 0.f, 0.f, 0.f};
        short8 b1 = pack8(g);

        unsigned short* tp = Y + (size_t)(tile0 + ti) * 1024;
#pragma unroll
        for (int m = 0; m < 4; ++m) {
            f32x4 acc = {0.f, 0.f, 0.f, 0.f};
            acc = MFMA16(afrag[m][0], b0, acc, 0, 0, 0);
            acc = MFMA16(afrag[m][1], b1, acc, 0, 0, 0);
            *(uint2*)(tp + (m * 2 + (quad >> 1)) * 128 + col * 8 + (quad & 1) * 4) =
                make_uint2(pk2(acc[0], acc[1]), pk2(acc[2], acc[3]));
#pragma unroll
            for (int r = 0; r < 4; ++r) {
                float v = acc[r];
                sacc[m][r] += v;
                s2acc[m][r] = fmaf(v, v, s2acc[m][r]);
            }
        }
        // rotate pipeline
        sA0 = sB0; sA1 = sB1;
        efA0 = efB0; efA1 = efB1; efA2 = efB2;
        idxB = idxC;
    }
    stats_epilogue(sacc, s2acc, tid, wv, col, quad, blockIdx.x, partials);
}

// ---------------------------------------------------------------------------
// Layer 2 STATS pass: read Y1, compute y2 = W2 * lrelu(n1(Y1)) per tile,
// accumulate y2 sum/sumsq, DISCARD y2 (no write -- y2 is recomputed in the
// fused stage23 once n2 is known). Eliminates 134 MB of HBM writes and keeps
// Y1 clean in L3 for the next pass. Reverse serpentine: stage1 wrote tiles
// ascending, so descending reads hit the L3-freshest tiles first.
__global__ __launch_bounds__(256) void mfma_stage2_stats(
        const unsigned short* __restrict__ Y,   // Y1 (read-only)
        const float* __restrict__ W,            // W2 (64, 64)
        const float* __restrict__ scale,        // n1 scale (B, 64)
        const float* __restrict__ shift,
        float* __restrict__ partials) {
    const int tid = threadIdx.x, lane = tid & 63, wv = tid >> 6;
    const int col = lane & 15, quad = lane >> 4;
    const int ablk = BLOCKS - 1 - blockIdx.x;
    const int b    = ablk >> 8;                 // 256 blocks per batch

    short8 afrag[4][2];
#pragma unroll
    for (int m = 0; m < 4; ++m)
#pragma unroll
        for (int kc = 0; kc < 2; ++kc) {
            const float4* wp = (const float4*)(W + (m * 16 + col) * 64 + kc * 32 + quad * 8);
            float4 w0 = wp[0], w1 = wp[1];
            float f[8] = {w0.x, w0.y, w0.z, w0.w, w1.x, w1.y, w1.z, w1.w};
            afrag[m][kc] = pack8(f);
        }
    float sc[2][8], sh[2][8];
#pragma unroll
    for (int kc = 0; kc < 2; ++kc) {
        const int c0 = (kc * 4 + quad) * 8;
#pragma unroll
        for (int j = 0; j < 8; ++j) {
            sc[kc][j] = scale[b * COUT + c0 + j];
            sh[kc][j] = shift[b * COUT + c0 + j];
        }
    }
    float sacc[4][4] = {{0.f}}, s2acc[4][4] = {{0.f}};
    const int tile0 = ablk * TPB + wv * TPW;
    const int off0 = quad * 128 + col * 8;

    // pipeline preload
    const unsigned short* tpA = Y + (size_t)tile0 * 1024;
    uint4 pA0 = *(const uint4*)(tpA + off0);
    uint4 pA1 = *(const uint4*)(tpA + 512 + off0);

    for (int ti = 0; ti < TPW; ++ti) {
        const unsigned short* tpB = Y + (size_t)(tile0 + min(ti + 1, TPW - 1)) * 1024;
        uint4 pB0 = *(const uint4*)(tpB + off0);
        uint4 pB1 = *(const uint4*)(tpB + 512 + off0);

        short8 b0 = xform(pA0, sc[0], sh[0]);
        short8 b1 = xform(pA1, sc[1], sh[1]);
#pragma unroll
        for (int m = 0; m < 4; ++m) {
            f32x4 acc = {0.f, 0.f, 0.f, 0.f};
            acc = MFMA16(afrag[m][0], b0, acc, 0, 0, 0);
            acc = MFMA16(afrag[m][1], b1, acc, 0, 0, 0);
#pragma unroll
            for (int r = 0; r < 4; ++r) {
                float v = acc[r];
                sacc[m][r] += v;
                s2acc[m][r] = fmaf(v, v, s2acc[m][r]);
            }
        }
        pA0 = pB0; pA1 = pB1;
    }
    stats_epilogue(sacc, s2acc, tid, wv, col, quad, ablk, partials);
}

// ---------------------------------------------------------------------------
// FUSED layers 2+3: read Y1 (forward; L3-warm from stage2_stats' reverse
// pass), recompute y2, quantize to bf16 (bit-identical to the old Y2 memory
// round-trip), transpose C-frag -> B-frag through a 2 KB wave-private LDS
// tile using the SAME addressing as the proven global Y store/load pair,
// apply n2 + lrelu, y3 GEMM, y3 stats + fp32 max/min compact records
// (stage_last machinery, unchanged). Y2 never touches HBM.
__global__ __launch_bounds__(256) void mfma_stage23(
        unsigned short* __restrict__ Y,         // Y1; R records written in-place
        const float* __restrict__ W2,           // (64, 64)
        const float* __restrict__ W3,           // (64, 64)
        const float* __restrict__ sc1g,         // n1 scale/shift (B, 64)
        const float* __restrict__ sh1g,
        const float* __restrict__ sc2g,         // n2 scale/shift (B, 64)
        const float* __restrict__ sh2g,
        float* __restrict__ partials) {
    const int tid = threadIdx.x, lane = tid & 63, wv = tid >> 6;
    const int col = lane & 15, quad = lane >> 4;
    const int ablk = blockIdx.x;
    const int b    = ablk >> 8;

    short8 afrag2[4][2], afrag3[4][2];
#pragma unroll
    for (int m = 0; m < 4; ++m)
#pragma unroll
        for (int kc = 0; kc < 2; ++kc) {
            const float4* wp2 = (const float4*)(W2 + (m * 16 + col) * 64 + kc * 32 + quad * 8);
            float4 a0 = wp2[0], a1 = wp2[1];
            float f2[8] = {a0.x, a0.y, a0.z, a0.w, a1.x, a1.y, a1.z, a1.w};
            afrag2[m][kc] = pack8(f2);
            const float4* wp3 = (const float4*)(W3 + (m * 16 + col) * 64 + kc * 32 + quad * 8);
            float4 c0 = wp3[0], c1 = wp3[1];
            float f3[8] = {c0.x, c0.y, c0.z, c0.w, c1.x, c1.y, c1.z, c1.w};
            afrag3[m][kc] = pack8(f3);
        }
    float sc1[2][8], sh1[2][8], sc2[2][8], sh2[2][8];
#pragma unroll
    for (int kc = 0; kc < 2; ++kc) {
        const int c0 = (kc * 4 + quad) * 8;
#pragma unroll
        for (int j = 0; j < 8; ++j) {
            sc1[kc][j] = sc1g[b * COUT + c0 + j];
            sh1[kc][j] = sh1g[b * COUT + c0 + j];
            sc2[kc][j] = sc2g[b * COUT + c0 + j];
            sh2[kc][j] = sh2g[b * COUT + c0 + j];
        }
    }
    float sacc[4][4] = {{0.f}}, s2acc[4][4] = {{0.f}};
    const int tile0 = ablk * TPB + wv * TPW;
    const int off0 = quad * 128 + col * 8;

    // wave-private: y2 transpose tile (2 KB) + max/min slice (8 KB, swizzled)
    __shared__ unsigned short tileT[4][1024];    // 8 KB
    __shared__ float ldsP[4][2048];              // 32 KB
    unsigned short* T = tileT[wv];
    float* P = ldsP[wv];
    const int swz = (col & 7) << 2;

    const unsigned short* tpA = Y + (size_t)tile0 * 1024;
    uint4 pA0 = *(const uint4*)(tpA + off0);
    uint4 pA1 = *(const uint4*)(tpA + 512 + off0);

#pragma unroll 1
    for (int pr = 0; pr < TPW / 2; ++pr) {
        float mx[4][4], mn[4][4];
#pragma unroll
        for (int m = 0; m < 4; ++m)
#pragma unroll
            for (int r = 0; r < 4; ++r) { mx[m][r] = -1e30f; mn[m][r] = 1e30f; }

#pragma unroll
        for (int hf = 0; hf < 2; ++hf) {
            const int ti = pr * 2 + hf;
            const unsigned short* tpB = Y + (size_t)(tile0 + min(ti + 1, TPW - 1)) * 1024;
            uint4 pB0 = *(const uint4*)(tpB + off0);
            uint4 pB1 = *(const uint4*)(tpB + 512 + off0);

            // ---- layer 2 recompute: y2 = W2 * lrelu(n1(y1))
            short8 b0 = xform(pA0, sc1[0], sh1[0]);
            short8 b1 = xform(pA1, sc1[1], sh1[1]);
#pragma unroll
            for (int m = 0; m < 4; ++m) {
                f32x4 a2 = {0.f, 0.f, 0.f, 0.f};
                a2 = MFMA16(afrag2[m][0], b0, a2, 0, 0, 0);
                a2 = MFMA16(afrag2[m][1], b1, a2, 0, 0, 0);
                // bf16-quantize + C->B transpose via LDS (same addr math as Y)
                *(uint2*)(T + (m * 2 + (quad >> 1)) * 128 + col * 8 + (quad & 1) * 4) =
                    make_uint2(pk2(a2[0], a2[1]), pk2(a2[2], a2[3]));
            }
            __builtin_amdgcn_wave_barrier();
            uint4 q0 = *(const uint4*)(T + off0);
            uint4 q1 = *(const uint4*)(T + 512 + off0);
            __builtin_amdgcn_wave_barrier();

            // ---- layer 3: y3 = W3 * lrelu(n2(y2))
            short8 c0 = xform(q0, sc2[0], sh2[0]);
            short8 c1 = xform(q1, sc2[1], sh2[1]);
#pragma unroll
            for (int m = 0; m < 4; ++m) {
                f32x4 acc = {0.f, 0.f, 0.f, 0.f};
                acc = MFMA16(afrag3[m][0], c0, acc, 0, 0, 0);
                acc = MFMA16(afrag3[m][1], c1, acc, 0, 0, 0);
#pragma unroll
                for (int r = 0; r < 4; ++r) {
                    float v = acc[r];
                    sacc[m][r] += v;
                    s2acc[m][r] = fmaf(v, v, s2acc[m][r]);
                    mx[m][r] = fmaxf(mx[m][r], v);
                    mn[m][r] = fminf(mn[m][r], v);
                }
            }
            pA0 = pB0; pA1 = pB1;
        }
        // stash per-lane (mx,mn) into the wave slice (8x ds_write_b128, 2-way max)
#pragma unroll
        for (int m = 0; m < 4; ++m) {
            const int fi0 = col * 128 + m * 32 + quad * 8;
            float4 lo = {mx[m][0], mn[m][0], mx[m][1], mn[m][1]};
            float4 hi = {mx[m][2], mn[m][2], mx[m][3], mn[m][3]};
            *(float4*)&P[fi0 ^ swz] = lo;
            *(float4*)&P[(fi0 + 4) ^ swz] = hi;
        }
        __builtin_amdgcn_wave_barrier();
        // wave-local reduce over the 16 edge-columns: lane owns channel o=lane
        float gx = -1e30f, gn = 1e30f;
#pragma unroll
        for (int cc = 0; cc < 16; ++cc) {
            const float2 v = *(const float2*)&P[(cc * 128 + lane * 2) ^ ((cc & 7) << 2)];
            gx = fmaxf(gx, v.x);
            gn = fminf(gn, v.y);
        }
        __builtin_amdgcn_wave_barrier();
        // compact R record into this wave's OWN already-read tile 2*pr region
        float* R = (float*)(Y + (size_t)(tile0 + 2 * pr) * 1024);
        R[lane]      = gx;
        R[64 + lane] = gn;
    }
    stats_epilogue(sacc, s2acc, tid, wv, col, quad, ablk, partials);
}

// ---------------------------------------------------------------------------
// Parallel finalize: one block per (o,b); 256 threads sum that batch's partials.
__global__ __launch_bounds__(256) void finalize_k(
        const float* __restrict__ partials,
        const float* __restrict__ gamma,
        const float* __restrict__ beta,
        float* __restrict__ scale,
        float* __restrict__ shift) {
    const int g = blockIdx.x;        // 0..255
    const int o = g >> 2, b = g & 3;
    const int k = threadIdx.x;       // 0..255
    const float* p = partials + (size_t)(b * 256 + k) * 128 + o * 2;
    float s = p[0], s2 = p[1];
    __shared__ float red[512];
    red[k] = s; red[256 + k] = s2;
    __syncthreads();
    for (int st = 128; st > 0; st >>= 1) {
        if (k < st) { red[k] += red[k + st]; red[256 + k] += red[256 + k + st]; }
        __syncthreads();
    }
    if (k == 0) {
        const float inv_n = 1.f / (float)PERB;
        float mean = red[0] * inv_n;
        float var  = red[256] * inv_n - mean * mean;
        float inv  = rsqrtf(var + EPS);
        float scv  = gamma[o] * inv;
        scale[b * COUT + o] = scv;
        shift[b * COUT + o] = beta[o] - mean * scv;
    }
}

// ---------------------------------------------------------------------------
// Final pool: read compact R records (fp32 max/min of pre-norm y3) from the
// per-(wv,pr) slots inside Y, apply affine norm (sign-aware), one lrelu.
__global__ __launch_bounds__(256) void pool_final(
        const unsigned short* __restrict__ Y,
        const float* __restrict__ scale,
        const float* __restrict__ shift,
        float* __restrict__ out) {
    const int t  = blockIdx.x * 256 + threadIdx.x;   // 0..262143
    const int og = t & 7;
    const int bn = t >> 3;
    const int b  = bn >> 13;
    const int ablk = bn >> 5;
    const int wv   = (bn >> 3) & 3;
    const int pr   = bn & 7;
    const float* base =
        (const float*)(Y + (size_t)(ablk * TPB + wv * TPW + 2 * pr) * 1024);
    float4 x0 = *(const float4*)(base + og * 8);
    float4 x1 = *(const float4*)(base + og * 8 + 4);
    float4 n0 = *(const float4*)(base + 64 + og * 8);
    float4 n1 = *(const float4*)(base + 68 + og * 8);
    float mxv[8] = {x0.x, x0.y, x0.z, x0.w, x1.x, x1.y, x1.z, x1.w};
    float mnv[8] = {n0.x, n0.y, n0.z, n0.w, n1.x, n1.y, n1.z, n1.w};
    float r[8];
#pragma unroll
    for (int j = 0; j < 8; ++j) {
        const int o = og * 8 + j;
        const float s = scale[b * COUT + o], h = shift[b * COUT + o];
        float m = (s >= 0.f ? mxv[j] : mnv[j]) * s + h;
        r[j] = lrelu(m);
    }
    float4* q = (float4*)(out + (size_t)bn * COUT + og * 8);
    q[0] = make_float4(r[0], r[1], r[2], r[3]);
    q[1] = make_float4(r[4], r[5], r[6], r[7]);
}

// ---------------------------------------------------------------------------
extern "C" void kernel_launch(void* const* d_in, const int* in_sizes, int n_in,
                              void* d_out, int out_size, void* d_ws, size_t ws_size,
                              hipStream_t stream) {
    const float* signal = (const float*)d_in[0];
    const void*  edges  = d_in[1];
    const float* ef     = (const float*)d_in[2];
    const float* W1 = (const float*)d_in[4];
    const float* g1 = (const float*)d_in[5];
    const float* b1 = (const float*)d_in[6];
    const float* W2 = (const float*)d_in[7];
    const float* g2 = (const float*)d_in[8];
    const float* b2 = (const float*)d_in[9];
    const float* W3 = (const float*)d_in[10];
    const float* g3 = (const float*)d_in[11];
    const float* b3 = (const float*)d_in[12];
    float* out = (float*)d_out;

    // Workspace: Y (134.2 MB) + partials (512 KB) + flag + 6x256 scale/shift
    unsigned short* Y = (unsigned short*)d_ws;
    const size_t YB = (size_t)E * COUT * sizeof(unsigned short);
    float* partials = (float*)((char*)d_ws + YB);
    char*  tail = (char*)d_ws + YB + (size_t)BLOCKS * 128 * sizeof(float);
    int*   flag = (int*)tail;
    float* ss   = (float*)(tail + 256);
    float *sc0 = ss,        *sh0 = ss + 256;
    float *sc1 = ss + 512,  *sh1 = ss + 768;
    float *sc2 = ss + 1024, *sh2 = ss + 1280;

    detect_i32<<<1, 64, 0, stream>>>((const unsigned int*)edges, flag);

    // L1: gather GEMM -> Y1 + y1 stats
    mfma_stage1<<<BLOCKS, 256, 0, stream>>>(signal, edges, ef, W1, Y, flag, partials);
    finalize_k<<<256, 256, 0, stream>>>(partials, g1, b1, sc0, sh0);

    // L2 stats-only pass (no Y2 write; reverse serpentine over L3-warm Y1)
    mfma_stage2_stats<<<BLOCKS, 256, 0, stream>>>(Y, W2, sc0, sh0, partials);
    finalize_k<<<256, 256, 0, stream>>>(partials, g2, b2, sc1, sh1);

    // Fused L2-recompute + L3 GEMM + max/min records (forward over warm Y1)
    mfma_stage23<<<BLOCKS, 256, 0, stream>>>(Y, W2, W3, sc0, sh0, sc1, sh1, partials);
    finalize_k<<<256, 256, 0, stream>>>(partials, g3, b3, sc2, sh2);

    pool_final<<<1024, 256, 0, stream>>>(Y, sc2, sh2, out);
}

// Round 7
// 162.053 us; speedup vs baseline: 3.9406x; 1.0248x over previous
//
#include <hip/hip_runtime.h>
#include <hip/hip_bf16.h>
#include <math.h>

// Problem constants (fixed by setup_inputs)
constexpr int B    = 4;
constexpr int N    = 8192;
constexpr int COUT = 64;
constexpr int E    = B * N * 32;      // 1048576 edges
constexpr int PERB = N * 32;          // 262144 elements per (b,o) norm group
constexpr int TILES  = E / 16;        // 65536 16-edge tiles
constexpr int TPW    = 16;            // tiles per wave
constexpr int TPB    = TPW * 4;       // 64 tiles per block
constexpr int BLOCKS = TILES / TPB;   // 1024 (256 per batch)
constexpr float EPS   = 1e-5f;
constexpr float SLOPE = 0.1f;

// Tiled-pack activation layout (bf16):
//   addr(c, e) = (e>>4)*1024 + (c>>3)*128 + (e&15)*8 + (c&7)    [ushort units]
// -> MFMA B-frag (8 ch of one edge) = one 16B load; C-store = 8B per m-tile.

typedef __attribute__((ext_vector_type(8))) short short8;
typedef __attribute__((ext_vector_type(4))) float f32x4;
#define MFMA16 __builtin_amdgcn_mfma_f32_16x16x32_bf16

union S8 { short8 s; unsigned int u[4]; };

__device__ __forceinline__ float bflo(unsigned int u) {
    union { unsigned int x; float f; } v; v.x = u << 16; return v.f;
}
__device__ __forceinline__ float bfhi(unsigned int u) {
    union { unsigned int x; float f; } v; v.x = u & 0xFFFF0000u; return v.f;
}
// packed f32x2 -> bf16x2 (RTNE); low 16 bits = a
__device__ __forceinline__ unsigned int pk2(float a, float b) {
    union { __hip_bfloat162 h; unsigned int u; } v;
    v.h = __float22bfloat162_rn(make_float2(a, b));
    return v.u;
}
__device__ __forceinline__ float lrelu(float z) {
    return fmaxf(z, SLOPE * z);
}
__device__ __forceinline__ short8 pack8(const float* f) {
    S8 r;
#pragma unroll
    for (int i = 0; i < 4; ++i) r.u[i] = pk2(f[2 * i], f[2 * i + 1]);
    return r.s;
}
// unpack 8 bf16, apply per-channel scale/shift + leaky relu, repack bf16
__device__ __forceinline__ short8 xform(uint4 raw, const float* sc, const float* sh) {
    unsigned int w[4] = {raw.x, raw.y, raw.z, raw.w};
    S8 r;
#pragma unroll
    for (int i = 0; i < 4; ++i) {
        float z0 = fmaf(bflo(w[i]), sc[2 * i],     sh[2 * i]);
        float z1 = fmaf(bfhi(w[i]), sc[2 * i + 1], sh[2 * i + 1]);
        r.u[i] = pk2(lrelu(z0), lrelu(z1));
    }
    return r.s;
}

// ---------------------------------------------------------------------------
__global__ void detect_i32(const unsigned int* __restrict__ w, int* __restrict__ flag) {
    unsigned long long m = __ballot(w[2 * threadIdx.x + 1] != 0u);
    if (threadIdx.x == 0) *flag = (m != 0ull) ? 1 : 0;
}

// ---------------------------------------------------------------------------
// Shared epilogue: per-(b,o) sum/sumsq partials -> partials[ablk][o*2+{0,1}]
__device__ __forceinline__ void stats_epilogue(
        float (&sacc)[4][4], float (&s2acc)[4][4],
        int tid, int wv, int col, int quad, int ablk,
        float* __restrict__ partials) {
    __shared__ float lds[2][4][64];
#pragma unroll
    for (int m = 0; m < 4; ++m)
#pragma unroll
        for (int r = 0; r < 4; ++r) {
            float s = sacc[m][r], s2 = s2acc[m][r];
#pragma unroll
            for (int d = 1; d < 16; d <<= 1) {
                s  += __shfl_xor(s,  d, 16);
                s2 += __shfl_xor(s2, d, 16);
            }
            if (col == 0) {
                int o = m * 16 + quad * 4 + r;
                lds[0][wv][o] = s;
                lds[1][wv][o] = s2;
            }
        }
    __syncthreads();
    if (tid < 64) {
        float s  = lds[0][0][tid] + lds[0][1][tid] + lds[0][2][tid] + lds[0][3][tid];
        float s2 = lds[1][0][tid] + lds[1][1][tid] + lds[1][2][tid] + lds[1][3][tid];
        ((float2*)(partials + (size_t)ablk * 128))[tid] = make_float2(s, s2);
    }
}

// ---------------------------------------------------------------------------
// Layer 1: gather + concat + MFMA (K=35 padded to 64). Software-pipelined:
// edge index 2-deep, signal/ef 1-deep prefetch (clamped, always in-bounds).
// EXACT round-0 code (VGPR=56, 58us). Occupancy levers are exhausted: grid
// doubling, 512-thr blocks, forced bounds, deeper ILP all measured neutral
// or negative (r1-r4) -- resident waves pin at ~12/CU regardless.
__global__ __launch_bounds__(256) void mfma_stage1(
        const float* __restrict__ signal,   // (BN, 32)
        const void*  __restrict__ edges,
        const float* __restrict__ ef,       // (E, 3)
        const float* __restrict__ W1,       // (64, 35)
        unsigned short* __restrict__ Y,
        const int* __restrict__ flag,
        float* __restrict__ partials) {
    const int tid = threadIdx.x, lane = tid & 63, wv = tid >> 6;
    const int col = lane & 15, quad = lane >> 4;

    short8 afrag[4][2];
#pragma unroll
    for (int m = 0; m < 4; ++m) {
        const float* wr = W1 + (m * 16 + col) * 35;
        float f[8];
#pragma unroll
        for (int j = 0; j < 8; ++j) f[j] = wr[quad * 8 + j];
        afrag[m][0] = pack8(f);
#pragma unroll
        for (int j = 0; j < 8; ++j) f[j] = (quad == 0 && j < 3) ? wr[32 + j] : 0.f;
        afrag[m][1] = pack8(f);
    }
    const bool is32 = (*flag != 0);
    const int* ip = (const int*)edges;
    const long long* lp = (const long long*)edges;

    float sacc[4][4] = {{0.f}}, s2acc[4][4] = {{0.f}};
    const int tile0 = blockIdx.x * TPB + wv * TPW;
    const int eW = tile0 * 16 + col;      // this lane's edge for tile ti: eW + 16*ti

    // pipeline preload
    long long idxA = is32 ? (long long)ip[eW] : lp[eW];
    long long idxB = is32 ? (long long)ip[min(eW + 16, E - 1)] : lp[min(eW + 16, E - 1)];
    const float* spA = signal + idxA * 32 + quad * 8;
    float4 sA0 = *(const float4*)spA;
    float4 sA1 = *(const float4*)(spA + 4);
    float efA0 = 0.f, efA1 = 0.f, efA2 = 0.f;
    if (quad == 0) {
        const float* p = ef + (size_t)eW * 3;
        efA0 = p[0]; efA1 = p[1]; efA2 = p[2];
    }

    for (int ti = 0; ti < TPW; ++ti) {
        const int eCur = eW + ti * 16;
        // prefetch idx two ahead, signal/ef one ahead
        const int eI = min(eCur + 32, E - 1);
        long long idxC = is32 ? (long long)ip[eI] : lp[eI];
        const float* spB = signal + idxB * 32 + quad * 8;
        float4 sB0 = *(const float4*)spB;
        float4 sB1 = *(const float4*)(spB + 4);
        float efB0 = 0.f, efB1 = 0.f, efB2 = 0.f;
        if (quad == 0) {
            const float* p = ef + (size_t)min(eCur + 16, E - 1) * 3;
            efB0 = p[0]; efB1 = p[1]; efB2 = p[2];
        }
        // compute current tile from A-buffers
        float f[8] = {sA0.x, sA0.y, sA0.z, sA0.w, sA1.x, sA1.y, sA1.z, sA1.w};
        short8 b0 = pack8(f);
        float g[8] = {efA0, efA1, efA2, 0.f, 0.f, 0.f, 0.f, 0.f};
        short8 b1 = pack8(g);

        unsigned short* tp = Y + (size_t)(tile0 + ti) * 1024;
#pragma unroll
        for (int m = 0; m < 4; ++m) {
            f32x4 acc = {0.f, 0.f, 0.f, 0.f};
            acc = MFMA16(afrag[m][0], b0, acc, 0, 0, 0);
            acc = MFMA16(afrag[m][1], b1, acc, 0, 0, 0);
            *(uint2*)(tp + (m * 2 + (quad >> 1)) * 128 + col * 8 + (quad & 1) * 4) =
                make_uint2(pk2(acc[0], acc[1]), pk2(acc[2], acc[3]));
#pragma unroll
            for (int r = 0; r < 4; ++r) {
                float v = acc[r];
                sacc[m][r] += v;
                s2acc[m][r] = fmaf(v, v, s2acc[m][r]);
            }
        }
        // rotate pipeline
        sA0 = sB0; sA1 = sB1;
        efA0 = efB0; efA1 = efB1; efA2 = efB2;
        idxB = idxC;
    }
    stats_epilogue(sacc, s2acc, tid, wv, col, quad, blockIdx.x, partials);
}

// ---------------------------------------------------------------------------
// Layer 2 STATS pass: read Y1, compute y2 = W2 * lrelu(n1(Y1)) per tile,
// accumulate y2 sum/sumsq, DISCARD y2 (no write -- y2 is recomputed in the
// fused stage23 once n2 is known). Eliminates 134 MB of HBM writes and keeps
// Y1 clean in L3 for the next pass. Measured 26us (r6). Reverse serpentine.
__global__ __launch_bounds__(256) void mfma_stage2_stats(
        const unsigned short* __restrict__ Y,   // Y1 (read-only)
        const float* __restrict__ W,            // W2 (64, 64)
        const float* __restrict__ scale,        // n1 scale (B, 64)
        const float* __restrict__ shift,
        float* __restrict__ partials) {
    const int tid = threadIdx.x, lane = tid & 63, wv = tid >> 6;
    const int col = lane & 15, quad = lane >> 4;
    const int ablk = BLOCKS - 1 - blockIdx.x;
    const int b    = ablk >> 8;                 // 256 blocks per batch

    short8 afrag[4][2];
#pragma unroll
    for (int m = 0; m < 4; ++m)
#pragma unroll
        for (int kc = 0; kc < 2; ++kc) {
            const float4* wp = (const float4*)(W + (m * 16 + col) * 64 + kc * 32 + quad * 8);
            float4 w0 = wp[0], w1 = wp[1];
            float f[8] = {w0.x, w0.y, w0.z, w0.w, w1.x, w1.y, w1.z, w1.w};
            afrag[m][kc] = pack8(f);
        }
    float sc[2][8], sh[2][8];
#pragma unroll
    for (int kc = 0; kc < 2; ++kc) {
        const int c0 = (kc * 4 + quad) * 8;
#pragma unroll
        for (int j = 0; j < 8; ++j) {
            sc[kc][j] = scale[b * COUT + c0 + j];
            sh[kc][j] = shift[b * COUT + c0 + j];
        }
    }
    float sacc[4][4] = {{0.f}}, s2acc[4][4] = {{0.f}};
    const int tile0 = ablk * TPB + wv * TPW;
    const int off0 = quad * 128 + col * 8;

    // pipeline preload
    const unsigned short* tpA = Y + (size_t)tile0 * 1024;
    uint4 pA0 = *(const uint4*)(tpA + off0);
    uint4 pA1 = *(const uint4*)(tpA + 512 + off0);

    for (int ti = 0; ti < TPW; ++ti) {
        const unsigned short* tpB = Y + (size_t)(tile0 + min(ti + 1, TPW - 1)) * 1024;
        uint4 pB0 = *(const uint4*)(tpB + off0);
        uint4 pB1 = *(const uint4*)(tpB + 512 + off0);

        short8 b0 = xform(pA0, sc[0], sh[0]);
        short8 b1 = xform(pA1, sc[1], sh[1]);
#pragma unroll
        for (int m = 0; m < 4; ++m) {
            f32x4 acc = {0.f, 0.f, 0.f, 0.f};
            acc = MFMA16(afrag[m][0], b0, acc, 0, 0, 0);
            acc = MFMA16(afrag[m][1], b1, acc, 0, 0, 0);
#pragma unroll
            for (int r = 0; r < 4; ++r) {
                float v = acc[r];
                sacc[m][r] += v;
                s2acc[m][r] = fmaf(v, v, s2acc[m][r]);
            }
        }
        pA0 = pB0; pA1 = pB1;
    }
    stats_epilogue(sacc, s2acc, tid, wv, col, quad, ablk, partials);
}

// ---------------------------------------------------------------------------
// FUSED layers 2+3, TRANSPOSE-FREE. After the layer-2 MFMA, lane (col,quad)
// holds y2 channels {m*16+quad*4+0..3} of edge col. Across the 4 quads these
// chunks cover k=0..31 (m=0,1) and k=32..63 (m=2,3) exactly once -- so they
// feed the layer-3 MFMA B-operand DIRECTLY under a permuted k-convention
// sigma(quad*8+j) = (j<4 ? quad*4+j : 16+quad*4+j-4) + kc*32, with afrag3 and
// n2 scale/shift loaded in the same permuted order. MFMA is sum_k A[o][k]B[k][e]
// so any consistent k-permutation is exact. This removes r6's tileT LDS
// round-trip: -8KB LDS (43008->34816, 4 blocks/CU), -1.05M bank conflicts,
// -2 wave_barriers per tile, shorter dep chain. bf16 quantize (pk2) kept.
__global__ __launch_bounds__(256) void mfma_stage23(
        unsigned short* __restrict__ Y,         // Y1; R records written in-place
        const float* __restrict__ W2,           // (64, 64)
        const float* __restrict__ W3,           // (64, 64)
        const float* __restrict__ sc1g,         // n1 scale/shift (B, 64)
        const float* __restrict__ sh1g,
        const float* __restrict__ sc2g,         // n2 scale/shift (B, 64)
        const float* __restrict__ sh2g,
        float* __restrict__ partials) {
    const int tid = threadIdx.x, lane = tid & 63, wv = tid >> 6;
    const int col = lane & 15, quad = lane >> 4;
    const int ablk = blockIdx.x;
    const int b    = ablk >> 8;

    short8 afrag2[4][2], afrag3[4][2];
#pragma unroll
    for (int m = 0; m < 4; ++m)
#pragma unroll
        for (int kc = 0; kc < 2; ++kc) {
            const float4* wp2 = (const float4*)(W2 + (m * 16 + col) * 64 + kc * 32 + quad * 8);
            float4 a0 = wp2[0], a1 = wp2[1];
            float f2[8] = {a0.x, a0.y, a0.z, a0.w, a1.x, a1.y, a1.z, a1.w};
            afrag2[m][kc] = pack8(f2);
            // permuted-k load of W3 (see kernel comment)
            const float* wr3 = W3 + (m * 16 + col) * 64 + kc * 32;
            float f3[8];
#pragma unroll
            for (int j = 0; j < 8; ++j) {
                const int ch = (j < 4) ? (quad * 4 + j) : (16 + quad * 4 + (j - 4));
                f3[j] = wr3[ch];
            }
            afrag3[m][kc] = pack8(f3);
        }
    float sc1[2][8], sh1[2][8], sc2[2][8], sh2[2][8];
#pragma unroll
    for (int kc = 0; kc < 2; ++kc) {
        const int c0 = (kc * 4 + quad) * 8;
#pragma unroll
        for (int j = 0; j < 8; ++j) {
            sc1[kc][j] = sc1g[b * COUT + c0 + j];
            sh1[kc][j] = sh1g[b * COUT + c0 + j];
            // permuted-k layout for the n2 affine (matches afrag3)
            const int ch = ((j < 4) ? (quad * 4 + j) : (16 + quad * 4 + (j - 4))) + kc * 32;
            sc2[kc][j] = sc2g[b * COUT + ch];
            sh2[kc][j] = sh2g[b * COUT + ch];
        }
    }
    float sacc[4][4] = {{0.f}}, s2acc[4][4] = {{0.f}};
    const int tile0 = ablk * TPB + wv * TPW;
    const int off0 = quad * 128 + col * 8;

    // wave-private max/min slice (fp32, col-swizzled) -- proven stage_last code
    __shared__ float ldsP[4][2048];              // 32 KB
    float* P = ldsP[wv];
    const int swz = (col & 7) << 2;

    const unsigned short* tpA = Y + (size_t)tile0 * 1024;
    uint4 pA0 = *(const uint4*)(tpA + off0);
    uint4 pA1 = *(const uint4*)(tpA + 512 + off0);

#pragma unroll 1
    for (int pr = 0; pr < TPW / 2; ++pr) {
        float mx[4][4], mn[4][4];
#pragma unroll
        for (int m = 0; m < 4; ++m)
#pragma unroll
            for (int r = 0; r < 4; ++r) { mx[m][r] = -1e30f; mn[m][r] = 1e30f; }

#pragma unroll
        for (int hf = 0; hf < 2; ++hf) {
            const int ti = pr * 2 + hf;
            const unsigned short* tpB = Y + (size_t)(tile0 + min(ti + 1, TPW - 1)) * 1024;
            uint4 pB0 = *(const uint4*)(tpB + off0);
            uint4 pB1 = *(const uint4*)(tpB + 512 + off0);

            // ---- layer 2 recompute: y2 = W2 * lrelu(n1(y1)), bf16-quantized
            short8 b0 = xform(pA0, sc1[0], sh1[0]);
            short8 b1 = xform(pA1, sc1[1], sh1[1]);
            unsigned int u[4][2];
#pragma unroll
            for (int m = 0; m < 4; ++m) {
                f32x4 a2 = {0.f, 0.f, 0.f, 0.f};
                a2 = MFMA16(afrag2[m][0], b0, a2, 0, 0, 0);
                a2 = MFMA16(afrag2[m][1], b1, a2, 0, 0, 0);
                u[m][0] = pk2(a2[0], a2[1]);
                u[m][1] = pk2(a2[2], a2[3]);
            }
            // direct C->B handoff under the permuted k-convention
            uint4 q0 = make_uint4(u[0][0], u[0][1], u[1][0], u[1][1]);
            uint4 q1 = make_uint4(u[2][0], u[2][1], u[3][0], u[3][1]);

            // ---- layer 3: y3 = W3 * lrelu(n2(y2))
            short8 c0 = xform(q0, sc2[0], sh2[0]);
            short8 c1 = xform(q1, sc2[1], sh2[1]);
#pragma unroll
            for (int m = 0; m < 4; ++m) {
                f32x4 acc = {0.f, 0.f, 0.f, 0.f};
                acc = MFMA16(afrag3[m][0], c0, acc, 0, 0, 0);
                acc = MFMA16(afrag3[m][1], c1, acc, 0, 0, 0);
#pragma unroll
                for (int r = 0; r < 4; ++r) {
                    float v = acc[r];
                    sacc[m][r] += v;
                    s2acc[m][r] = fmaf(v, v, s2acc[m][r]);
                    mx[m][r] = fmaxf(mx[m][r], v);
                    mn[m][r] = fminf(mn[m][r], v);
                }
            }
            pA0 = pB0; pA1 = pB1;
        }
        // stash per-lane (mx,mn) into the wave slice (8x ds_write_b128, 2-way max)
#pragma unroll
        for (int m = 0; m < 4; ++m) {
            const int fi0 = col * 128 + m * 32 + quad * 8;
            float4 lo = {mx[m][0], mn[m][0], mx[m][1], mn[m][1]};
            float4 hi = {mx[m][2], mn[m][2], mx[m][3], mn[m][3]};
            *(float4*)&P[fi0 ^ swz] = lo;
            *(float4*)&P[(fi0 + 4) ^ swz] = hi;
        }
        __builtin_amdgcn_wave_barrier();
        // wave-local reduce over the 16 edge-columns: lane owns channel o=lane
        float gx = -1e30f, gn = 1e30f;
#pragma unroll
        for (int cc = 0; cc < 16; ++cc) {
            const float2 v = *(const float2*)&P[(cc * 128 + lane * 2) ^ ((cc & 7) << 2)];
            gx = fmaxf(gx, v.x);
            gn = fminf(gn, v.y);
        }
        __builtin_amdgcn_wave_barrier();
        // compact R record into this wave's OWN already-read tile 2*pr region
        float* R = (float*)(Y + (size_t)(tile0 + 2 * pr) * 1024);
        R[lane]      = gx;
        R[64 + lane] = gn;
    }
    stats_epilogue(sacc, s2acc, tid, wv, col, quad, ablk, partials);
}

// ---------------------------------------------------------------------------
// Parallel finalize: one block per (o,b); 256 threads sum that batch's partials.
__global__ __launch_bounds__(256) void finalize_k(
        const float* __restrict__ partials,
        const float* __restrict__ gamma,
        const float* __restrict__ beta,
        float* __restrict__ scale,
        float* __restrict__ shift) {
    const int g = blockIdx.x;        // 0..255
    const int o = g >> 2, b = g & 3;
    const int k = threadIdx.x;       // 0..255
    const float* p = partials + (size_t)(b * 256 + k) * 128 + o * 2;
    float s = p[0], s2 = p[1];
    __shared__ float red[512];
    red[k] = s; red[256 + k] = s2;
    __syncthreads();
    for (int st = 128; st > 0; st >>= 1) {
        if (k < st) { red[k] += red[k + st]; red[256 + k] += red[256 + k + st]; }
        __syncthreads();
    }
    if (k == 0) {
        const float inv_n = 1.f / (float)PERB;
        float mean = red[0] * inv_n;
        float var  = red[256] * inv_n - mean * mean;
        float inv  = rsqrtf(var + EPS);
        float scv  = gamma[o] * inv;
        scale[b * COUT + o] = scv;
        shift[b * COUT + o] = beta[o] - mean * scv;
    }
}

// ---------------------------------------------------------------------------
// Final pool: read compact R records (fp32 max/min of pre-norm y3) from the
// per-(wv,pr) slots inside Y, apply affine norm (sign-aware), one lrelu.
__global__ __launch_bounds__(256) void pool_final(
        const unsigned short* __restrict__ Y,
        const float* __restrict__ scale,
        const float* __restrict__ shift,
        float* __restrict__ out) {
    const int t  = blockIdx.x * 256 + threadIdx.x;   // 0..262143
    const int og = t & 7;
    const int bn = t >> 3;
    const int b  = bn >> 13;
    const int ablk = bn >> 5;
    const int wv   = (bn >> 3) & 3;
    const int pr   = bn & 7;
    const float* base =
        (const float*)(Y + (size_t)(ablk * TPB + wv * TPW + 2 * pr) * 1024);
    float4 x0 = *(const float4*)(base + og * 8);
    float4 x1 = *(const float4*)(base + og * 8 + 4);
    float4 n0 = *(const float4*)(base + 64 + og * 8);
    float4 n1 = *(const float4*)(base + 68 + og * 8);
    float mxv[8] = {x0.x, x0.y, x0.z, x0.w, x1.x, x1.y, x1.z, x1.w};
    float mnv[8] = {n0.x, n0.y, n0.z, n0.w, n1.x, n1.y, n1.z, n1.w};
    float r[8];
#pragma unroll
    for (int j = 0; j < 8; ++j) {
        const int o = og * 8 + j;
        const float s = scale[b * COUT + o], h = shift[b * COUT + o];
        float m = (s >= 0.f ? mxv[j] : mnv[j]) * s + h;
        r[j] = lrelu(m);
    }
    float4* q = (float4*)(out + (size_t)bn * COUT + og * 8);
    q[0] = make_float4(r[0], r[1], r[2], r[3]);
    q[1] = make_float4(r[4], r[5], r[6], r[7]);
}

// ---------------------------------------------------------------------------
extern "C" void kernel_launch(void* const* d_in, const int* in_sizes, int n_in,
                              void* d_out, int out_size, void* d_ws, size_t ws_size,
                              hipStream_t stream) {
    const float* signal = (const float*)d_in[0];
    const void*  edges  = d_in[1];
    const float* ef     = (const float*)d_in[2];
    const float* W1 = (const float*)d_in[4];
    const float* g1 = (const float*)d_in[5];
    const float* b1 = (const float*)d_in[6];
    const float* W2 = (const float*)d_in[7];
    const float* g2 = (const float*)d_in[8];
    const float* b2 = (const float*)d_in[9];
    const float* W3 = (const float*)d_in[10];
    const float* g3 = (const float*)d_in[11];
    const float* b3 = (const float*)d_in[12];
    float* out = (float*)d_out;

    // Workspace: Y (134.2 MB) + partials (512 KB) + flag + 6x256 scale/shift
    unsigned short* Y = (unsigned short*)d_ws;
    const size_t YB = (size_t)E * COUT * sizeof(unsigned short);
    float* partials = (float*)((char*)d_ws + YB);
    char*  tail = (char*)d_ws + YB + (size_t)BLOCKS * 128 * sizeof(float);
    int*   flag = (int*)tail;
    float* ss   = (float*)(tail + 256);
    float *sc0 = ss,        *sh0 = ss + 256;
    float *sc1 = ss + 512,  *sh1 = ss + 768;
    float *sc2 = ss + 1024, *sh2 = ss + 1280;

    detect_i32<<<1, 64, 0, stream>>>((const unsigned int*)edges, flag);

    // L1: gather GEMM -> Y1 + y1 stats
    mfma_stage1<<<BLOCKS, 256, 0, stream>>>(signal, edges, ef, W1, Y, flag, partials);
    finalize_k<<<256, 256, 0, stream>>>(partials, g1, b1, sc0, sh0);

    // L2 stats-only pass (no Y2 write; reverse serpentine over L3-warm Y1)
    mfma_stage2_stats<<<BLOCKS, 256, 0, stream>>>(Y, W2, sc0, sh0, partials);
    finalize_k<<<256, 256, 0, stream>>>(partials, g2, b2, sc1, sh1);

    // Fused L2-recompute + L3 GEMM + max/min records (forward over warm Y1)
    mfma_stage23<<<BLOCKS, 256, 0, stream>>>(Y, W2, W3, sc0, sh0, sc1, sh1, partials);
    finalize_k<<<256, 256, 0, stream>>>(partials, g3, b3, sc2, sh2);

    pool_final<<<1024, 256, 0, stream>>>(Y, sc2, sh2, out);
}